// Round 6
// baseline (836.197 us; speedup 1.0000x reference)
//
#include <hip/hip_runtime.h>
#include <hip/hip_bf16.h>

using bf16 = __hip_bfloat16;
typedef __attribute__((ext_vector_type(8))) short short8;
typedef __attribute__((ext_vector_type(4))) float floatx4;
typedef __attribute__((ext_vector_type(16))) float floatx16;

#define MFMA_BF16(a, b, c) __builtin_amdgcn_mfma_f32_16x16x32_bf16((a), (b), (c), 0, 0, 0)
#define MFMA32(a, b, c) __builtin_amdgcn_mfma_f32_32x32x16_bf16((a), (b), (c), 0, 0, 0)

__device__ __forceinline__ void gload_lds16(const bf16* g, bf16* l) {
  __builtin_amdgcn_global_load_lds((__attribute__((address_space(1))) void*)g,
                                   (__attribute__((address_space(3))) void*)l,
                                   16, 0, 0);
}

__device__ __forceinline__ unsigned short bfbits(float f) {
  bf16 b = __float2bfloat16(f);
  return *reinterpret_cast<unsigned short*>(&b);
}

// K-scale: SCALE * log2(e) folded so flash uses raw v_exp_f32 (=exp2)
#define KSCALE 0.18033688011112042f

// ---------- probe dtype (seq_mask words are {0,0x3F800000} iff fp32) + cvt mask ----
__global__ __launch_bounds__(256)
void probemask_k(const void* __restrict__ msrc, bf16* __restrict__ dst,
                 int* __restrict__ flag) {
  __shared__ int any;
  const int tid = threadIdx.x;
  if (tid == 0) any = 0;
  __syncthreads();
  const unsigned* mw = (const unsigned*)msrc;
  int bad = 0;
#pragma unroll
  for (int i = 0; i < 4; i++) {
    unsigned w = mw[tid * 4 + i];
    if (w != 0u && w != 0x3F800000u) bad = 1;
  }
  if (bad) atomicOr(&any, 1);
  __syncthreads();
  const int isbf = any;  // 1 => inputs bf16, 0 => fp32
  if (tid == 0) flag[0] = isbf;
  if (isbf) {
#pragma unroll
    for (int i = 0; i < 2; i++)
      ((int4*)dst)[tid * 2 + i] = ((const int4*)msrc)[tid * 2 + i];
  } else {
#pragma unroll
    for (int i = 0; i < 4; i++) {
      float4 v = ((const float4*)msrc)[tid * 4 + i];
      int o = tid * 16 + i * 4;
      dst[o + 0] = __float2bfloat16(v.x);
      dst[o + 1] = __float2bfloat16(v.y);
      dst[o + 2] = __float2bfloat16(v.z);
      dst[o + 3] = __float2bfloat16(v.w);
    }
  }
}

// ---------- convert x to bf16 (fp32 path only; bf16 path reads src directly) ----
__global__ __launch_bounds__(256)
void cvt_k(const void* __restrict__ src, bf16* __restrict__ dst, int n,
           const int* __restrict__ flag) {
  if (*flag) return;
  int i = (blockIdx.x * 256 + threadIdx.x) * 4;
  if (i >= n) return;
  float4 v = ((const float4*)src)[i >> 2];
  dst[i + 0] = __float2bfloat16(v.x);
  dst[i + 1] = __float2bfloat16(v.y);
  dst[i + 2] = __float2bfloat16(v.z);
  dst[i + 3] = __float2bfloat16(v.w);
}

// ---------- both weight transposes (+cvt) in one launch: in[1024][C] -> out[C][1024]
__global__ __launch_bounds__(256)
void transpose2_k(const void* __restrict__ in0, bf16* __restrict__ out0,
                  const void* __restrict__ in1, bf16* __restrict__ out1,
                  const int* __restrict__ flag) {
  __shared__ bf16 tile[32][33];
  const int isbf = *flag;
  constexpr int R = 1024;
  const void* in;
  bf16* out;
  int C, bx;
  if (blockIdx.x < 96) { in = in0; out = out0; C = 3072; bx = blockIdx.x * 32; }
  else                 { in = in1; out = out1; C = 1024; bx = (blockIdx.x - 96) * 32; }
  int by = blockIdx.y * 32;
  int tx = threadIdx.x & 31, ty = threadIdx.x >> 5;
#pragma unroll
  for (int i = 0; i < 4; i++) {
    size_t idx = (size_t)(by + ty + i * 8) * C + bx + tx;
    tile[ty + i * 8][tx] =
        isbf ? ((const bf16*)in)[idx] : __float2bfloat16(((const float*)in)[idx]);
  }
  __syncthreads();
#pragma unroll
  for (int i = 0; i < 4; i++)
    out[(size_t)(bx + ty + i * 8) * R + by + tx] = tile[tx][ty + i * 8];
}

// ---------------- GEMM: C[M,N] = A[M,1024] @ Bt[N,1024]^T ----------------
// 128x128 tiles. MODE 0: A = x [4096,1024], N=3072; scatters Q->[b,h,n,d],
// K and V in FRAGMENT-PACKED layouts (consumed by flash_k as wave-contiguous
// 1KB coalesced loads): packed elem (tile t=key>>6, half, c, gh, l31, j) at
// t*4096 + half*2048 + c*512 + gh*256 + l31*8 + j.
//   K: half=kt=(key>>5)&1, l31=key&31, d=(c*2+gh)*8+j  (pre-scaled KSCALE*mask)
//   V: half=dt=d>>5,       l31=d&31,   key_local=(c*2+gh)*8+j
// MODE 1: A = AO [4096,1024] (linear), N=1024 -> Co (bf16/f32 per flag).
template <int MODE>
__global__ __launch_bounds__(256, 2)
void gemm_k(const bf16* __restrict__ A, const bf16* __restrict__ Aalt,
            const bf16* __restrict__ Bt,
            bf16* __restrict__ Qo, bf16* __restrict__ Ko, bf16* __restrict__ Vo,
            void* __restrict__ Co, const bf16* __restrict__ Mk,
            const int* __restrict__ flag) {
  constexpr int K = 1024;
  __shared__ __align__(16) bf16 As[128 * 32];
  __shared__ __align__(16) bf16 Bs[128 * 32];

  const int tid = threadIdx.x;
  const int lane = tid & 63;
  const int wv = tid >> 6;
  const int wm = wv & 1, wn = wv >> 1;
  const int l15 = lane & 15, quad = lane >> 4;

  const int bm = blockIdx.y * 128;
  const int bn = blockIdx.x * 128;

  const int sml = tid >> 2;
  const int sg = (tid & 3) ^ ((sml >> 1) & 3);

  const int isbf = *flag;
  const bf16* Ab = (MODE == 0 && isbf) ? Aalt : A;

  floatx4 acc[4][4] = {};

  for (int k0 = 0; k0 < K; k0 += 32) {
    __syncthreads();
    const bf16* a0 = Ab + (size_t)(bm + sml) * K + k0 + sg * 8;
    gload_lds16(a0, &As[tid * 8]);
    gload_lds16(a0 + (size_t)64 * K, &As[2048 + tid * 8]);
    const bf16* b0 = Bt + (size_t)(bn + sml) * K + k0 + sg * 8;
    gload_lds16(b0, &Bs[tid * 8]);
    gload_lds16(b0 + (size_t)64 * K, &Bs[2048 + tid * 8]);
    __syncthreads();

    short8 af[4], bfr[4];
#pragma unroll
    for (int mi = 0; mi < 4; mi++) {
      int m = wm * 64 + mi * 16 + l15;
      af[mi] = *(const short8*)&As[m * 32 + ((quad ^ ((m >> 1) & 3)) * 8)];
    }
#pragma unroll
    for (int ni = 0; ni < 4; ni++) {
      int n = wn * 64 + ni * 16 + l15;
      bfr[ni] = *(const short8*)&Bs[n * 32 + ((quad ^ ((n >> 1) & 3)) * 8)];
    }
#pragma unroll
    for (int mi = 0; mi < 4; mi++)
#pragma unroll
      for (int ni = 0; ni < 4; ni++)
        acc[mi][ni] = MFMA_BF16(af[mi], bfr[ni], acc[mi][ni]);
  }

#pragma unroll
  for (int mi = 0; mi < 4; mi++) {
    const int row0 = bm + wm * 64 + mi * 16 + quad * 4;
#pragma unroll
    for (int ni = 0; ni < 4; ni++) {
      const int col = bn + wn * 64 + ni * 16 + l15;
      if (MODE == 0) {
        const int sec = col >> 10;
        const int cc = col & 1023;
        const int h = cc >> 6, d = cc & 63;
        const int b_idx = row0 >> 11;
        const int nn0 = row0 & 2047;
        if (sec == 0) {
          bf16* dst = Qo + (size_t)(b_idx * 16 + h) * 131072 + (size_t)nn0 * 64 + d;
#pragma unroll
          for (int r = 0; r < 4; r++) dst[r * 64] = __float2bfloat16(acc[mi][ni][r]);
        } else if (sec == 1) {
          // fold SCALE*log2e*mask_j into K rows; packed-fragment K layout.
          // key = nn0 + r: t,kt fixed (nn0%4==0), l31 = (nn0&31)+r.
          const bf16* mrow = Mk + (size_t)b_idx * 2048 + nn0;
          const int t = nn0 >> 6, kt = (nn0 >> 5) & 1, l31r = nn0 & 31;
          const int g = d >> 3, j = d & 7;
          bf16* dst = Ko + (size_t)(b_idx * 16 + h) * 131072 + t * 4096 + kt * 2048 +
                      (g >> 1) * 512 + (g & 1) * 256 + l31r * 8 + j;
#pragma unroll
          for (int r = 0; r < 4; r++)
            dst[r * 8] = __float2bfloat16(acc[mi][ni][r] * KSCALE *
                                          __bfloat162float(mrow[r]));
        } else {
          // packed-fragment V layout. key = nn0 + r: j = (nn0&7)+r (consecutive,
          // since nn0%4==0 => j0 in {0,4}), all other fields fixed.
          const int t = nn0 >> 6;
          const int kl = nn0 & 63;
          const int g = kl >> 3, j0 = kl & 7;
          bf16* dst = Vo + (size_t)(b_idx * 16 + h) * 131072 + t * 4096 +
                      (d >> 5) * 2048 + (g >> 1) * 512 + (g & 1) * 256 + (d & 31) * 8 + j0;
          ushort4 u;
          u.x = bfbits(acc[mi][ni][0]);
          u.y = bfbits(acc[mi][ni][1]);
          u.z = bfbits(acc[mi][ni][2]);
          u.w = bfbits(acc[mi][ni][3]);
          *(ushort4*)dst = u;
        }
      } else {
        if (isbf) {
          bf16* C2 = (bf16*)Co;
#pragma unroll
          for (int r = 0; r < 4; r++)
            C2[(size_t)(row0 + r) * 1024 + col] = __float2bfloat16(acc[mi][ni][r]);
        } else {
          float* C2 = (float*)Co;
#pragma unroll
          for (int r = 0; r < 4; r++)
            C2[(size_t)(row0 + r) * 1024 + col] = acc[mi][ni][r];
        }
      }
    }
  }
}

// ---------------- flash attention v12 (v10b + one-step S pipelining) ------------
// Minimal delta from the PASSING v10b (r4, 49.8us): the S-MFMA for tile it+1 is
// moved from "top of iteration it+1" to "after softmax(it), adjacent to PV(it)".
// Carried state is a single register tile sN (renamed to s at loop top — pure
// SSA rename); kf is loaded and consumed within the same iteration. The merged
// MFMA region has 3 independent accumulator chains (sN, o_acc[0], o_acc[1]), so
// the next iteration starts directly at softmax — the ~930cy/wave-iter serial
// chain (the r2/r4-measured limiter; MfmaUtil 27.8% == issue/chain ratio)
// shortens to ~softmax+cluster. All load expressions, softmax/pf asm (T12),
// PV indexing, combine, epilogue are verbatim v10b. Deferred rsum shfl
// (lane-local partials, one shfl at end — exact reassociation). No barriers in
// the main loop; direct-L2 KV via gemm1's fragment-packed layout; XCD swizzle.
__global__ __launch_bounds__(512, 4)
void flash_k(const bf16* __restrict__ Q, const bf16* __restrict__ Kp,
             const bf16* __restrict__ Vp, bf16* __restrict__ AO) {
  __shared__ __align__(16) float cb[4 * 64 * 32];  // 32 KB combine buffer
  __shared__ float rbuf[4 * 64];                   // 1 KB rsum combine

  const int tid = threadIdx.x;
  const int lane = tid & 63;
  const int l31 = lane & 31;
  const int l5h = lane >> 5;  // 0..1
  const int w = tid >> 6;     // 0..7
  const int rg = w & 3;       // row group (32 rows each)
  const int half = w >> 2;    // KV half: 0 -> keys 0..1023, 1 -> 1024..2047

  // XCD-aware swizzle (bijective, 512 % 8 == 0): consecutive work units of the
  // same head land on the same XCD -> KV stays in that XCD's L2.
  const int bid = blockIdx.x;
  const int wk = (bid & 7) * 64 + (bid >> 3);
  const int qt = wk & 15;  // 16 tiles x 128 rows
  const int hl = wk >> 4;  // b*16+h
  const int b_idx = hl >> 4, h = hl & 15;

  const bf16* Qh = Q + (size_t)hl * 131072;
  const int lo = l5h * 256 + l31 * 8;  // per-lane elem offset inside a fragment
  const bf16* kptr = Kp + (size_t)hl * 131072 + (size_t)(half * 16) * 4096 + lo;
  const bf16* vptr = Vp + (size_t)hl * 131072 + (size_t)(half * 16) * 4096 + lo;

  const int qbase = qt * 128 + rg * 32;
  const int qrow = qbase + l31;

  // Q fragments (B-operand of S^T): B[k=d][n=row]: lane n=l31, k=c*16+l5h*8+j
  short8 qf[4];
#pragma unroll
  for (int c = 0; c < 4; c++)
    qf[c] = *(const short8*)&Qh[(size_t)qrow * 64 + c * 16 + l5h * 8];

  floatx16 o_acc[2] = {};  // O^T: col=l31=row, d = dt*32 + (reg&3)+8*(reg>>2)+4*l5h
  float rsm0 = 0.f, rsm1 = 0.f, rsm2 = 0.f, rsm3 = 0.f;  // lane-local partials
  const floatx16 zero16 = {};

  // prologue: sN = S(0); kptr points at the CURRENT tile's K (tile 0)
  short8 kf[4];
#pragma unroll
  for (int c = 0; c < 4; c++) kf[c] = *(const short8*)(kptr + c * 512);
  floatx16 sN = zero16;
  __builtin_amdgcn_s_setprio(1);
#pragma unroll
  for (int c = 0; c < 4; c++) sN = MFMA32(kf[c], qf[c], sN);
  __builtin_amdgcn_s_setprio(0);

#pragma unroll 1
  for (int it = 0; it < 32; ++it) {
    const int kv = it & 1;  // which 32-key half of the 64-key packed tile
    floatx16 s = sN;        // scores of tile `it` (computed last iteration)

    // V loads for this tile (consumed in PV below; softmax covers the latency)
    short8 vf[4];
#pragma unroll
    for (int dt = 0; dt < 2; dt++)
#pragma unroll
      for (int ch = 0; ch < 2; ch++)
        vf[dt * 2 + ch] = *(const short8*)(vptr + dt * 2048 + (kv * 2 + ch) * 512);

    // K load for tile it+1 (consumed by the sN cluster at the end of this iter)
    if (it < 31) {
      kptr += 2048;
#pragma unroll
      for (int c = 0; c < 4; c++) kf[c] = *(const short8*)(kptr + c * 512);
    }

    // p = exp2(s); lane owns one softmax row (16 of this tile's 32 keys; the
    // other 16 live in lane^32 — combined once at the end, additive softmax)
#pragma unroll
    for (int r = 0; r < 16; r += 4) {
      const float p0 = __builtin_amdgcn_exp2f(s[r + 0]);
      const float p1 = __builtin_amdgcn_exp2f(s[r + 1]);
      const float p2 = __builtin_amdgcn_exp2f(s[r + 2]);
      const float p3 = __builtin_amdgcn_exp2f(s[r + 3]);
      s[r + 0] = p0; rsm0 += p0;
      s[r + 1] = p1; rsm1 += p1;
      s[r + 2] = p2; rsm2 += p2;
      s[r + 3] = p3; rsm3 += p3;
    }

    // pf[ch][j] = P[key=ch*16+l5h*8+j][row=l31], built in-register (T12).
    // Held: s[reg] = P[row=l31][key=(reg&3)+8*(reg>>2)+4*l5h].
    short8 pf[2];
#pragma unroll
    for (int ch = 0; ch < 2; ch++) {
      const int rb = ch * 8;
      unsigned x0, x1, y0, y1;
      asm("v_cvt_pk_bf16_f32 %0, %1, %2" : "=v"(x0) : "v"(s[rb + 0]), "v"(s[rb + 1]));
      asm("v_cvt_pk_bf16_f32 %0, %1, %2" : "=v"(x1) : "v"(s[rb + 2]), "v"(s[rb + 3]));
      asm("v_cvt_pk_bf16_f32 %0, %1, %2" : "=v"(y0) : "v"(s[rb + 4]), "v"(s[rb + 5]));
      asm("v_cvt_pk_bf16_f32 %0, %1, %2" : "=v"(y1) : "v"(s[rb + 6]), "v"(s[rb + 7]));
      asm("v_permlane32_swap_b32 %0, %1" : "+v"(x0), "+v"(y0));
      asm("v_permlane32_swap_b32 %0, %1" : "+v"(x1), "+v"(y1));
      union { unsigned u[4]; short8 v; } cv;
      cv.u[0] = x0; cv.u[1] = x1; cv.u[2] = y0; cv.u[3] = y1;
      pf[ch] = cv.v;
    }

    // merged MFMA region: S(it+1) (fresh kf) + PV(it) — 3 independent chains
    if (it < 31) {
      sN = zero16;
      __builtin_amdgcn_s_setprio(1);
      sN = MFMA32(kf[0], qf[0], sN);
      o_acc[0] = MFMA32(vf[0], pf[0], o_acc[0]);
      sN = MFMA32(kf[1], qf[1], sN);
      o_acc[1] = MFMA32(vf[2], pf[0], o_acc[1]);
      sN = MFMA32(kf[2], qf[2], sN);
      o_acc[0] = MFMA32(vf[1], pf[1], o_acc[0]);
      sN = MFMA32(kf[3], qf[3], sN);
      o_acc[1] = MFMA32(vf[3], pf[1], o_acc[1]);
      __builtin_amdgcn_s_setprio(0);
    } else {
      __builtin_amdgcn_s_setprio(1);
      o_acc[0] = MFMA32(vf[0], pf[0], o_acc[0]);
      o_acc[1] = MFMA32(vf[2], pf[0], o_acc[1]);
      o_acc[0] = MFMA32(vf[1], pf[1], o_acc[0]);
      o_acc[1] = MFMA32(vf[3], pf[1], o_acc[1]);
      __builtin_amdgcn_s_setprio(0);
    }

    vptr += kv ? 4096 : 0;  // V packed-tile (64-key) stride, advance every 2 iters
  }

  float rsum = (rsm0 + rsm1) + (rsm2 + rsm3);
  rsum += __shfl_xor(rsum, 32, 64);

  // ---- combine KV halves: waves 4-7 hand o_acc/rsum to partner via LDS ----
  if (w >= 4) {
    const int slot = (w - 4) * 64 + lane;
    float4* dst = (float4*)(cb + (size_t)slot * 32);
#pragma unroll
    for (int dt = 0; dt < 2; dt++)
#pragma unroll
      for (int q = 0; q < 4; q++) {
        float4 v = make_float4(o_acc[dt][q * 4 + 0], o_acc[dt][q * 4 + 1],
                               o_acc[dt][q * 4 + 2], o_acc[dt][q * 4 + 3]);
        dst[(dt * 4 + q) ^ (lane & 7)] = v;  // xor-swizzle: conflict-free
      }
    rbuf[slot] = rsum;
  }
  __syncthreads();
  if (w < 4) {
    const int slot = w * 64 + lane;
    const float4* src = (const float4*)(cb + (size_t)slot * 32);
#pragma unroll
    for (int dt = 0; dt < 2; dt++)
#pragma unroll
      for (int q = 0; q < 4; q++) {
        float4 v = src[(dt * 4 + q) ^ (lane & 7)];
        o_acc[dt][q * 4 + 0] += v.x;
        o_acc[dt][q * 4 + 1] += v.y;
        o_acc[dt][q * 4 + 2] += v.z;
        o_acc[dt][q * 4 + 3] += v.w;
      }
    rsum += rbuf[slot];

    // epilogue: lane owns q-row qbase+l31; AO linear [b*2048+n][1024], col=h*64+d
    const float rinv = 1.f / rsum;
    bf16* orow = AO + (size_t)(b_idx * 2048 + qbase + l31) * 1024 + h * 64;
#pragma unroll
    for (int dt = 0; dt < 2; dt++)
#pragma unroll
      for (int rg2 = 0; rg2 < 4; rg2++) {
        ushort4 u;
        u.x = bfbits(o_acc[dt][rg2 * 4 + 0] * rinv);
        u.y = bfbits(o_acc[dt][rg2 * 4 + 1] * rinv);
        u.z = bfbits(o_acc[dt][rg2 * 4 + 2] * rinv);
        u.w = bfbits(o_acc[dt][rg2 * 4 + 3] * rinv);
        *(ushort4*)&orow[dt * 32 + rg2 * 8 + l5h * 4] = u;
      }
  }
}

extern "C" void kernel_launch(void* const* d_in, const int* in_sizes, int n_in,
                              void* d_out, int out_size, void* d_ws, size_t ws_size,
                              hipStream_t stream) {
  const void* x     = d_in[0];  // [2,2048,1024]  bf16 or fp32 (probed)
  const void* mask  = d_in[1];  // [2,2048]
  const void* w_qkv = d_in[2];  // [1024,3072]
  const void* w_out = d_in[3];  // [1024,1024]

  bf16* ws    = (bf16*)d_ws;
  bf16* xb    = ws;                     // 4194304 (fp32 path only; dead after gemm1)
  bf16* AO    = ws;                     // alias of xb, linear [4096,1024]
  bf16* wqkvT = ws + 4194304;           // 3145728
  bf16* woutT = wqkvT + 3145728;        // 1048576
  bf16* Qb    = woutT + 1048576;        // 4194304
  bf16* Kp    = Qb + 4194304;           // 4194304 (fragment-packed K)
  bf16* maskb = Kp + 4194304;           // 4096
  int*  flag  = (int*)(maskb + 4096);
  bf16* Vp    = (bf16*)d_out;           // 4194304 packed V (dead before gemm2 writes)

  probemask_k<<<1, 256, 0, stream>>>(mask, maskb, flag);
  cvt_k<<<4096, 256, 0, stream>>>(x, xb, 4194304, flag);
  transpose2_k<<<dim3(128, 32), 256, 0, stream>>>(w_qkv, wqkvT, w_out, woutT, flag);
  gemm_k<0><<<dim3(24, 32), 256, 0, stream>>>(xb, (const bf16*)x, wqkvT, Qb, Kp, Vp,
                                              nullptr, maskb, flag);
  flash_k<<<512, 512, 0, stream>>>(Qb, Kp, Vp, AO);
  gemm_k<1><<<dim3(8, 32), 256, 0, stream>>>(AO, nullptr, woutT, nullptr, nullptr,
                                             nullptr, d_out, nullptr, flag);
}

// Round 7
// 507.919 us; speedup vs baseline: 1.6463x; 1.6463x over previous
//
#include <hip/hip_runtime.h>
#include <hip/hip_bf16.h>

using bf16 = __hip_bfloat16;
typedef __attribute__((ext_vector_type(8))) short short8;
typedef __attribute__((ext_vector_type(4))) float floatx4;
typedef __attribute__((ext_vector_type(16))) float floatx16;

#define MFMA_BF16(a, b, c) __builtin_amdgcn_mfma_f32_16x16x32_bf16((a), (b), (c), 0, 0, 0)
#define MFMA32(a, b, c) __builtin_amdgcn_mfma_f32_32x32x16_bf16((a), (b), (c), 0, 0, 0)

__device__ __forceinline__ void gload_lds16(const bf16* g, bf16* l) {
  __builtin_amdgcn_global_load_lds((__attribute__((address_space(1))) void*)g,
                                   (__attribute__((address_space(3))) void*)l,
                                   16, 0, 0);
}

__device__ __forceinline__ unsigned short bfbits(float f) {
  bf16 b = __float2bfloat16(f);
  return *reinterpret_cast<unsigned short*>(&b);
}

// K-scale: SCALE * log2(e) folded so flash uses raw v_exp_f32 (=exp2)
#define KSCALE 0.18033688011112042f

// ---------- probe dtype (seq_mask words are {0,0x3F800000} iff fp32) + cvt mask ----
__global__ __launch_bounds__(256)
void probemask_k(const void* __restrict__ msrc, bf16* __restrict__ dst,
                 int* __restrict__ flag) {
  __shared__ int any;
  const int tid = threadIdx.x;
  if (tid == 0) any = 0;
  __syncthreads();
  const unsigned* mw = (const unsigned*)msrc;
  int bad = 0;
#pragma unroll
  for (int i = 0; i < 4; i++) {
    unsigned w = mw[tid * 4 + i];
    if (w != 0u && w != 0x3F800000u) bad = 1;
  }
  if (bad) atomicOr(&any, 1);
  __syncthreads();
  const int isbf = any;  // 1 => inputs bf16, 0 => fp32
  if (tid == 0) flag[0] = isbf;
  if (isbf) {
#pragma unroll
    for (int i = 0; i < 2; i++)
      ((int4*)dst)[tid * 2 + i] = ((const int4*)msrc)[tid * 2 + i];
  } else {
#pragma unroll
    for (int i = 0; i < 4; i++) {
      float4 v = ((const float4*)msrc)[tid * 4 + i];
      int o = tid * 16 + i * 4;
      dst[o + 0] = __float2bfloat16(v.x);
      dst[o + 1] = __float2bfloat16(v.y);
      dst[o + 2] = __float2bfloat16(v.z);
      dst[o + 3] = __float2bfloat16(v.w);
    }
  }
}

// ---------- convert x to bf16 (fp32 path only; bf16 path reads src directly) ----
__global__ __launch_bounds__(256)
void cvt_k(const void* __restrict__ src, bf16* __restrict__ dst, int n,
           const int* __restrict__ flag) {
  if (*flag) return;
  int i = (blockIdx.x * 256 + threadIdx.x) * 4;
  if (i >= n) return;
  float4 v = ((const float4*)src)[i >> 2];
  dst[i + 0] = __float2bfloat16(v.x);
  dst[i + 1] = __float2bfloat16(v.y);
  dst[i + 2] = __float2bfloat16(v.z);
  dst[i + 3] = __float2bfloat16(v.w);
}

// ---------- both weight transposes (+cvt) in one launch: in[1024][C] -> out[C][1024]
__global__ __launch_bounds__(256)
void transpose2_k(const void* __restrict__ in0, bf16* __restrict__ out0,
                  const void* __restrict__ in1, bf16* __restrict__ out1,
                  const int* __restrict__ flag) {
  __shared__ bf16 tile[32][33];
  const int isbf = *flag;
  constexpr int R = 1024;
  const void* in;
  bf16* out;
  int C, bx;
  if (blockIdx.x < 96) { in = in0; out = out0; C = 3072; bx = blockIdx.x * 32; }
  else                 { in = in1; out = out1; C = 1024; bx = (blockIdx.x - 96) * 32; }
  int by = blockIdx.y * 32;
  int tx = threadIdx.x & 31, ty = threadIdx.x >> 5;
#pragma unroll
  for (int i = 0; i < 4; i++) {
    size_t idx = (size_t)(by + ty + i * 8) * C + bx + tx;
    tile[ty + i * 8][tx] =
        isbf ? ((const bf16*)in)[idx] : __float2bfloat16(((const float*)in)[idx]);
  }
  __syncthreads();
#pragma unroll
  for (int i = 0; i < 4; i++)
    out[(size_t)(bx + ty + i * 8) * R + by + tx] = tile[tx][ty + i * 8];
}

// ---------------- GEMM: C[M,N] = A[M,1024] @ Bt[N,1024]^T ----------------
// 128x128 tiles. MODE 0: A = x [4096,1024], N=3072; scatters Q->[b,h,n,d],
// K and V in FRAGMENT-PACKED layouts (consumed by flash_k as wave-contiguous
// 1KB coalesced loads): packed elem (tile t=key>>6, half, c, gh, l31, j) at
// t*4096 + half*2048 + c*512 + gh*256 + l31*8 + j.
//   K: half=kt=(key>>5)&1, l31=key&31, d=(c*2+gh)*8+j  (pre-scaled KSCALE*mask)
//   V: half=dt=d>>5,       l31=d&31,   key_local=(c*2+gh)*8+j
// MODE 1: A = AO [4096,1024] (linear), N=1024 -> Co (bf16/f32 per flag).
template <int MODE>
__global__ __launch_bounds__(256, 2)
void gemm_k(const bf16* __restrict__ A, const bf16* __restrict__ Aalt,
            const bf16* __restrict__ Bt,
            bf16* __restrict__ Qo, bf16* __restrict__ Ko, bf16* __restrict__ Vo,
            void* __restrict__ Co, const bf16* __restrict__ Mk,
            const int* __restrict__ flag) {
  constexpr int K = 1024;
  __shared__ __align__(16) bf16 As[128 * 32];
  __shared__ __align__(16) bf16 Bs[128 * 32];

  const int tid = threadIdx.x;
  const int lane = tid & 63;
  const int wv = tid >> 6;
  const int wm = wv & 1, wn = wv >> 1;
  const int l15 = lane & 15, quad = lane >> 4;

  const int bm = blockIdx.y * 128;
  const int bn = blockIdx.x * 128;

  const int sml = tid >> 2;
  const int sg = (tid & 3) ^ ((sml >> 1) & 3);

  const int isbf = *flag;
  const bf16* Ab = (MODE == 0 && isbf) ? Aalt : A;

  floatx4 acc[4][4] = {};

  for (int k0 = 0; k0 < K; k0 += 32) {
    __syncthreads();
    const bf16* a0 = Ab + (size_t)(bm + sml) * K + k0 + sg * 8;
    gload_lds16(a0, &As[tid * 8]);
    gload_lds16(a0 + (size_t)64 * K, &As[2048 + tid * 8]);
    const bf16* b0 = Bt + (size_t)(bn + sml) * K + k0 + sg * 8;
    gload_lds16(b0, &Bs[tid * 8]);
    gload_lds16(b0 + (size_t)64 * K, &Bs[2048 + tid * 8]);
    __syncthreads();

    short8 af[4], bfr[4];
#pragma unroll
    for (int mi = 0; mi < 4; mi++) {
      int m = wm * 64 + mi * 16 + l15;
      af[mi] = *(const short8*)&As[m * 32 + ((quad ^ ((m >> 1) & 3)) * 8)];
    }
#pragma unroll
    for (int ni = 0; ni < 4; ni++) {
      int n = wn * 64 + ni * 16 + l15;
      bfr[ni] = *(const short8*)&Bs[n * 32 + ((quad ^ ((n >> 1) & 3)) * 8)];
    }
#pragma unroll
    for (int mi = 0; mi < 4; mi++)
#pragma unroll
      for (int ni = 0; ni < 4; ni++)
        acc[mi][ni] = MFMA_BF16(af[mi], bfr[ni], acc[mi][ni]);
  }

#pragma unroll
  for (int mi = 0; mi < 4; mi++) {
    const int row0 = bm + wm * 64 + mi * 16 + quad * 4;
#pragma unroll
    for (int ni = 0; ni < 4; ni++) {
      const int col = bn + wn * 64 + ni * 16 + l15;
      if (MODE == 0) {
        const int sec = col >> 10;
        const int cc = col & 1023;
        const int h = cc >> 6, d = cc & 63;
        const int b_idx = row0 >> 11;
        const int nn0 = row0 & 2047;
        if (sec == 0) {
          bf16* dst = Qo + (size_t)(b_idx * 16 + h) * 131072 + (size_t)nn0 * 64 + d;
#pragma unroll
          for (int r = 0; r < 4; r++) dst[r * 64] = __float2bfloat16(acc[mi][ni][r]);
        } else if (sec == 1) {
          // fold SCALE*log2e*mask_j into K rows; packed-fragment K layout.
          // key = nn0 + r: t,kt fixed (nn0%4==0), l31 = (nn0&31)+r.
          const bf16* mrow = Mk + (size_t)b_idx * 2048 + nn0;
          const int t = nn0 >> 6, kt = (nn0 >> 5) & 1, l31r = nn0 & 31;
          const int g = d >> 3, j = d & 7;
          bf16* dst = Ko + (size_t)(b_idx * 16 + h) * 131072 + t * 4096 + kt * 2048 +
                      (g >> 1) * 512 + (g & 1) * 256 + l31r * 8 + j;
#pragma unroll
          for (int r = 0; r < 4; r++)
            dst[r * 8] = __float2bfloat16(acc[mi][ni][r] * KSCALE *
                                          __bfloat162float(mrow[r]));
        } else {
          // packed-fragment V layout. key = nn0 + r: j = (nn0&7)+r (consecutive,
          // since nn0%4==0 => j0 in {0,4}), all other fields fixed.
          const int t = nn0 >> 6;
          const int kl = nn0 & 63;
          const int g = kl >> 3, j0 = kl & 7;
          bf16* dst = Vo + (size_t)(b_idx * 16 + h) * 131072 + t * 4096 +
                      (d >> 5) * 2048 + (g >> 1) * 512 + (g & 1) * 256 + (d & 31) * 8 + j0;
          ushort4 u;
          u.x = bfbits(acc[mi][ni][0]);
          u.y = bfbits(acc[mi][ni][1]);
          u.z = bfbits(acc[mi][ni][2]);
          u.w = bfbits(acc[mi][ni][3]);
          *(ushort4*)dst = u;
        }
      } else {
        if (isbf) {
          bf16* C2 = (bf16*)Co;
#pragma unroll
          for (int r = 0; r < 4; r++)
            C2[(size_t)(row0 + r) * 1024 + col] = __float2bfloat16(acc[mi][ni][r]);
        } else {
          float* C2 = (float*)Co;
#pragma unroll
          for (int r = 0; r < 4; r++)
            C2[(size_t)(row0 + r) * 1024 + col] = acc[mi][ni][r];
        }
      }
    }
  }
}

// ---------------- flash attention v13 (v12 pipelining, spill-free) --------------
// v12 (correct but 690us) spilled: the `s = sN` copy kept TWO floatx16 score
// vectors live through softmax -> ~135 live VGPR > the 128 cap of (512,4) ->
// allocator spilled the vectors to scratch (2.17GB/dispatch WRITE_SIZE, VGPR=64).
// v13 = v12 minus the copy: softmax runs IN PLACE on the carried sN; pf is
// extracted; only then is sN zeroed for the next tile's S cluster. Live set at
// the merged MFMA region: qf16+kf16+vf16+pf8+o_acc32+sN16 ~= 119 < 128.
// Schedule (the r2/r4-diagnosed serial-chain fix) is unchanged: per iter
// [vf loads][kf(it+1) loads][softmax(it)+pf][merged cluster: S(it+1) chain
// interleaved with the two PV(it) chains]. No main-loop barriers; direct-L2 KV
// (fragment-packed, 1KB wave-contiguous loads); XCD swizzle; deferred rsum.
__global__ __launch_bounds__(512, 4)
void flash_k(const bf16* __restrict__ Q, const bf16* __restrict__ Kp,
             const bf16* __restrict__ Vp, bf16* __restrict__ AO) {
  __shared__ __align__(16) float cb[4 * 64 * 32];  // 32 KB combine buffer
  __shared__ float rbuf[4 * 64];                   // 1 KB rsum combine

  const int tid = threadIdx.x;
  const int lane = tid & 63;
  const int l31 = lane & 31;
  const int l5h = lane >> 5;  // 0..1
  const int w = tid >> 6;     // 0..7
  const int rg = w & 3;       // row group (32 rows each)
  const int half = w >> 2;    // KV half: 0 -> keys 0..1023, 1 -> 1024..2047

  // XCD-aware swizzle (bijective, 512 % 8 == 0): consecutive work units of the
  // same head land on the same XCD -> KV stays in that XCD's L2.
  const int bid = blockIdx.x;
  const int wk = (bid & 7) * 64 + (bid >> 3);
  const int qt = wk & 15;  // 16 tiles x 128 rows
  const int hl = wk >> 4;  // b*16+h
  const int b_idx = hl >> 4, h = hl & 15;

  const bf16* Qh = Q + (size_t)hl * 131072;
  const int lo = l5h * 256 + l31 * 8;  // per-lane elem offset inside a fragment
  const bf16* kptr = Kp + (size_t)hl * 131072 + (size_t)(half * 16) * 4096 + lo;
  const bf16* vptr = Vp + (size_t)hl * 131072 + (size_t)(half * 16) * 4096 + lo;

  const int qbase = qt * 128 + rg * 32;
  const int qrow = qbase + l31;

  // Q fragments (B-operand of S^T): B[k=d][n=row]: lane n=l31, k=c*16+l5h*8+j
  short8 qf[4];
#pragma unroll
  for (int c = 0; c < 4; c++)
    qf[c] = *(const short8*)&Qh[(size_t)qrow * 64 + c * 16 + l5h * 8];

  floatx16 o_acc[2] = {};  // O^T: col=l31=row, d = dt*32 + (reg&3)+8*(reg>>2)+4*l5h
  float rsm0 = 0.f, rsm1 = 0.f, rsm2 = 0.f, rsm3 = 0.f;  // lane-local partials
  const floatx16 zero16 = {};

  // prologue: sN = S(0); kptr points at the CURRENT tile's K (tile 0)
  short8 kf[4];
#pragma unroll
  for (int c = 0; c < 4; c++) kf[c] = *(const short8*)(kptr + c * 512);
  floatx16 sN = zero16;
  __builtin_amdgcn_s_setprio(1);
#pragma unroll
  for (int c = 0; c < 4; c++) sN = MFMA32(kf[c], qf[c], sN);
  __builtin_amdgcn_s_setprio(0);

#pragma unroll 1
  for (int it = 0; it < 32; ++it) {
    const int kv = it & 1;  // which 32-key half of the 64-key packed tile

    // V loads for this tile (consumed in PV below; softmax covers the latency)
    short8 vf[4];
#pragma unroll
    for (int dt = 0; dt < 2; dt++)
#pragma unroll
      for (int ch = 0; ch < 2; ch++)
        vf[dt * 2 + ch] = *(const short8*)(vptr + dt * 2048 + (kv * 2 + ch) * 512);

    // K load for tile it+1 (consumed by the sN cluster at the end of this iter)
    if (it < 31) {
      kptr += 2048;
#pragma unroll
      for (int c = 0; c < 4; c++) kf[c] = *(const short8*)(kptr + c * 512);
    }

    // p = exp2(sN) IN PLACE (no copy: keeps one score vector live, not two).
    // Lane owns one softmax row (16 of this tile's 32 keys; other 16 in
    // lane^32 — combined once at the end, additive softmax).
#pragma unroll
    for (int r = 0; r < 16; r += 4) {
      const float p0 = __builtin_amdgcn_exp2f(sN[r + 0]);
      const float p1 = __builtin_amdgcn_exp2f(sN[r + 1]);
      const float p2 = __builtin_amdgcn_exp2f(sN[r + 2]);
      const float p3 = __builtin_amdgcn_exp2f(sN[r + 3]);
      sN[r + 0] = p0; rsm0 += p0;
      sN[r + 1] = p1; rsm1 += p1;
      sN[r + 2] = p2; rsm2 += p2;
      sN[r + 3] = p3; rsm3 += p3;
    }

    // pf[ch][j] = P[key=ch*16+l5h*8+j][row=l31], built in-register (T12).
    // Held: sN[reg] = P[row=l31][key=(reg&3)+8*(reg>>2)+4*l5h].
    short8 pf[2];
#pragma unroll
    for (int ch = 0; ch < 2; ch++) {
      const int rb = ch * 8;
      unsigned x0, x1, y0, y1;
      asm("v_cvt_pk_bf16_f32 %0, %1, %2" : "=v"(x0) : "v"(sN[rb + 0]), "v"(sN[rb + 1]));
      asm("v_cvt_pk_bf16_f32 %0, %1, %2" : "=v"(x1) : "v"(sN[rb + 2]), "v"(sN[rb + 3]));
      asm("v_cvt_pk_bf16_f32 %0, %1, %2" : "=v"(y0) : "v"(sN[rb + 4]), "v"(sN[rb + 5]));
      asm("v_cvt_pk_bf16_f32 %0, %1, %2" : "=v"(y1) : "v"(sN[rb + 6]), "v"(sN[rb + 7]));
      asm("v_permlane32_swap_b32 %0, %1" : "+v"(x0), "+v"(y0));
      asm("v_permlane32_swap_b32 %0, %1" : "+v"(x1), "+v"(y1));
      union { unsigned u[4]; short8 v; } cv;
      cv.u[0] = x0; cv.u[1] = x1; cv.u[2] = y0; cv.u[3] = y1;
      pf[ch] = cv.v;
    }
    // sN is now dead (pf holds P); reuse its registers for the next S tile.

    // merged MFMA region: S(it+1) (fresh kf) + PV(it) — 3 independent chains
    if (it < 31) {
      sN = zero16;
      __builtin_amdgcn_s_setprio(1);
      sN = MFMA32(kf[0], qf[0], sN);
      o_acc[0] = MFMA32(vf[0], pf[0], o_acc[0]);
      sN = MFMA32(kf[1], qf[1], sN);
      o_acc[1] = MFMA32(vf[2], pf[0], o_acc[1]);
      sN = MFMA32(kf[2], qf[2], sN);
      o_acc[0] = MFMA32(vf[1], pf[1], o_acc[0]);
      sN = MFMA32(kf[3], qf[3], sN);
      o_acc[1] = MFMA32(vf[3], pf[1], o_acc[1]);
      __builtin_amdgcn_s_setprio(0);
    } else {
      __builtin_amdgcn_s_setprio(1);
      o_acc[0] = MFMA32(vf[0], pf[0], o_acc[0]);
      o_acc[1] = MFMA32(vf[2], pf[0], o_acc[1]);
      o_acc[0] = MFMA32(vf[1], pf[1], o_acc[0]);
      o_acc[1] = MFMA32(vf[3], pf[1], o_acc[1]);
      __builtin_amdgcn_s_setprio(0);
    }

    vptr += kv ? 4096 : 0;  // V packed-tile (64-key) stride, advance every 2 iters
  }

  float rsum = (rsm0 + rsm1) + (rsm2 + rsm3);
  rsum += __shfl_xor(rsum, 32, 64);

  // ---- combine KV halves: waves 4-7 hand o_acc/rsum to partner via LDS ----
  if (w >= 4) {
    const int slot = (w - 4) * 64 + lane;
    float4* dst = (float4*)(cb + (size_t)slot * 32);
#pragma unroll
    for (int dt = 0; dt < 2; dt++)
#pragma unroll
      for (int q = 0; q < 4; q++) {
        float4 v = make_float4(o_acc[dt][q * 4 + 0], o_acc[dt][q * 4 + 1],
                               o_acc[dt][q * 4 + 2], o_acc[dt][q * 4 + 3]);
        dst[(dt * 4 + q) ^ (lane & 7)] = v;  // xor-swizzle: conflict-free
      }
    rbuf[slot] = rsum;
  }
  __syncthreads();
  if (w < 4) {
    const int slot = w * 64 + lane;
    const float4* src = (const float4*)(cb + (size_t)slot * 32);
#pragma unroll
    for (int dt = 0; dt < 2; dt++)
#pragma unroll
      for (int q = 0; q < 4; q++) {
        float4 v = src[(dt * 4 + q) ^ (lane & 7)];
        o_acc[dt][q * 4 + 0] += v.x;
        o_acc[dt][q * 4 + 1] += v.y;
        o_acc[dt][q * 4 + 2] += v.z;
        o_acc[dt][q * 4 + 3] += v.w;
      }
    rsum += rbuf[slot];

    // epilogue: lane owns q-row qbase+l31; AO linear [b*2048+n][1024], col=h*64+d
    const float rinv = 1.f / rsum;
    bf16* orow = AO + (size_t)(b_idx * 2048 + qbase + l31) * 1024 + h * 64;
#pragma unroll
    for (int dt = 0; dt < 2; dt++)
#pragma unroll
      for (int rg2 = 0; rg2 < 4; rg2++) {
        ushort4 u;
        u.x = bfbits(o_acc[dt][rg2 * 4 + 0] * rinv);
        u.y = bfbits(o_acc[dt][rg2 * 4 + 1] * rinv);
        u.z = bfbits(o_acc[dt][rg2 * 4 + 2] * rinv);
        u.w = bfbits(o_acc[dt][rg2 * 4 + 3] * rinv);
        *(ushort4*)&orow[dt * 32 + rg2 * 8 + l5h * 4] = u;
      }
  }
}

extern "C" void kernel_launch(void* const* d_in, const int* in_sizes, int n_in,
                              void* d_out, int out_size, void* d_ws, size_t ws_size,
                              hipStream_t stream) {
  const void* x     = d_in[0];  // [2,2048,1024]  bf16 or fp32 (probed)
  const void* mask  = d_in[1];  // [2,2048]
  const void* w_qkv = d_in[2];  // [1024,3072]
  const void* w_out = d_in[3];  // [1024,1024]

  bf16* ws    = (bf16*)d_ws;
  bf16* xb    = ws;                     // 4194304 (fp32 path only; dead after gemm1)
  bf16* AO    = ws;                     // alias of xb, linear [4096,1024]
  bf16* wqkvT = ws + 4194304;           // 3145728
  bf16* woutT = wqkvT + 3145728;        // 1048576
  bf16* Qb    = woutT + 1048576;        // 4194304
  bf16* Kp    = Qb + 4194304;           // 4194304 (fragment-packed K)
  bf16* maskb = Kp + 4194304;           // 4096
  int*  flag  = (int*)(maskb + 4096);
  bf16* Vp    = (bf16*)d_out;           // 4194304 packed V (dead before gemm2 writes)

  probemask_k<<<1, 256, 0, stream>>>(mask, maskb, flag);
  cvt_k<<<4096, 256, 0, stream>>>(x, xb, 4194304, flag);
  transpose2_k<<<dim3(128, 32), 256, 0, stream>>>(w_qkv, wqkvT, w_out, woutT, flag);
  gemm_k<0><<<dim3(24, 32), 256, 0, stream>>>(xb, (const bf16*)x, wqkvT, Qb, Kp, Vp,
                                              nullptr, maskb, flag);
  flash_k<<<512, 512, 0, stream>>>(Qb, Kp, Vp, AO);
  gemm_k<1><<<dim3(8, 32), 256, 0, stream>>>(AO, nullptr, woutT, nullptr, nullptr,
                                             nullptr, d_out, nullptr, flag);
}

// Round 8
// 195.579 us; speedup vs baseline: 4.2755x; 2.5970x over previous
//
#include <hip/hip_runtime.h>
#include <hip/hip_bf16.h>

using bf16 = __hip_bfloat16;
typedef __attribute__((ext_vector_type(8))) short short8;
typedef __attribute__((ext_vector_type(4))) float floatx4;
typedef __attribute__((ext_vector_type(16))) float floatx16;

#define MFMA_BF16(a, b, c) __builtin_amdgcn_mfma_f32_16x16x32_bf16((a), (b), (c), 0, 0, 0)
#define MFMA32(a, b, c) __builtin_amdgcn_mfma_f32_32x32x16_bf16((a), (b), (c), 0, 0, 0)

__device__ __forceinline__ void gload_lds16(const bf16* g, bf16* l) {
  __builtin_amdgcn_global_load_lds((__attribute__((address_space(1))) void*)g,
                                   (__attribute__((address_space(3))) void*)l,
                                   16, 0, 0);
}

__device__ __forceinline__ unsigned short bfbits(float f) {
  bf16 b = __float2bfloat16(f);
  return *reinterpret_cast<unsigned short*>(&b);
}

// K-scale: SCALE * log2(e) folded so flash uses raw v_exp_f32 (=exp2)
#define KSCALE 0.18033688011112042f

// ---------- probe dtype (seq_mask words are {0,0x3F800000} iff fp32) + cvt mask ----
__global__ __launch_bounds__(256)
void probemask_k(const void* __restrict__ msrc, bf16* __restrict__ dst,
                 int* __restrict__ flag) {
  __shared__ int any;
  const int tid = threadIdx.x;
  if (tid == 0) any = 0;
  __syncthreads();
  const unsigned* mw = (const unsigned*)msrc;
  int bad = 0;
#pragma unroll
  for (int i = 0; i < 4; i++) {
    unsigned w = mw[tid * 4 + i];
    if (w != 0u && w != 0x3F800000u) bad = 1;
  }
  if (bad) atomicOr(&any, 1);
  __syncthreads();
  const int isbf = any;  // 1 => inputs bf16, 0 => fp32
  if (tid == 0) flag[0] = isbf;
  if (isbf) {
#pragma unroll
    for (int i = 0; i < 2; i++)
      ((int4*)dst)[tid * 2 + i] = ((const int4*)msrc)[tid * 2 + i];
  } else {
#pragma unroll
    for (int i = 0; i < 4; i++) {
      float4 v = ((const float4*)msrc)[tid * 4 + i];
      int o = tid * 16 + i * 4;
      dst[o + 0] = __float2bfloat16(v.x);
      dst[o + 1] = __float2bfloat16(v.y);
      dst[o + 2] = __float2bfloat16(v.z);
      dst[o + 3] = __float2bfloat16(v.w);
    }
  }
}

// ---------- convert x to bf16 (fp32 path only; bf16 path reads src directly) ----
__global__ __launch_bounds__(256)
void cvt_k(const void* __restrict__ src, bf16* __restrict__ dst, int n,
           const int* __restrict__ flag) {
  if (*flag) return;
  int i = (blockIdx.x * 256 + threadIdx.x) * 4;
  if (i >= n) return;
  float4 v = ((const float4*)src)[i >> 2];
  dst[i + 0] = __float2bfloat16(v.x);
  dst[i + 1] = __float2bfloat16(v.y);
  dst[i + 2] = __float2bfloat16(v.z);
  dst[i + 3] = __float2bfloat16(v.w);
}

// ---------- both weight transposes (+cvt) in one launch: in[1024][C] -> out[C][1024]
__global__ __launch_bounds__(256)
void transpose2_k(const void* __restrict__ in0, bf16* __restrict__ out0,
                  const void* __restrict__ in1, bf16* __restrict__ out1,
                  const int* __restrict__ flag) {
  __shared__ bf16 tile[32][33];
  const int isbf = *flag;
  constexpr int R = 1024;
  const void* in;
  bf16* out;
  int C, bx;
  if (blockIdx.x < 96) { in = in0; out = out0; C = 3072; bx = blockIdx.x * 32; }
  else                 { in = in1; out = out1; C = 1024; bx = (blockIdx.x - 96) * 32; }
  int by = blockIdx.y * 32;
  int tx = threadIdx.x & 31, ty = threadIdx.x >> 5;
#pragma unroll
  for (int i = 0; i < 4; i++) {
    size_t idx = (size_t)(by + ty + i * 8) * C + bx + tx;
    tile[ty + i * 8][tx] =
        isbf ? ((const bf16*)in)[idx] : __float2bfloat16(((const float*)in)[idx]);
  }
  __syncthreads();
#pragma unroll
  for (int i = 0; i < 4; i++)
    out[(size_t)(bx + ty + i * 8) * R + by + tx] = tile[tx][ty + i * 8];
}

// ---------------- GEMM: C[M,N] = A[M,1024] @ Bt[N,1024]^T ----------------
// 128x128 tiles. MODE 0: A = x [4096,1024], N=3072; scatters Q->[b,h,n,d],
// K and V in FRAGMENT-PACKED layouts (consumed by flash_k as wave-contiguous
// 1KB coalesced loads): packed elem (tile t=key>>6, half, c, gh, l31, j) at
// t*4096 + half*2048 + c*512 + gh*256 + l31*8 + j.
//   K: half=kt=(key>>5)&1, l31=key&31, d=(c*2+gh)*8+j  (pre-scaled KSCALE*mask)
//   V: half=dt=d>>5,       l31=d&31,   key_local=(c*2+gh)*8+j
// MODE 1: A = AO [4096,1024] (linear), N=1024 -> Co (bf16/f32 per flag).
template <int MODE>
__global__ __launch_bounds__(256, 2)
void gemm_k(const bf16* __restrict__ A, const bf16* __restrict__ Aalt,
            const bf16* __restrict__ Bt,
            bf16* __restrict__ Qo, bf16* __restrict__ Ko, bf16* __restrict__ Vo,
            void* __restrict__ Co, const bf16* __restrict__ Mk,
            const int* __restrict__ flag) {
  constexpr int K = 1024;
  __shared__ __align__(16) bf16 As[128 * 32];
  __shared__ __align__(16) bf16 Bs[128 * 32];

  const int tid = threadIdx.x;
  const int lane = tid & 63;
  const int wv = tid >> 6;
  const int wm = wv & 1, wn = wv >> 1;
  const int l15 = lane & 15, quad = lane >> 4;

  const int bm = blockIdx.y * 128;
  const int bn = blockIdx.x * 128;

  const int sml = tid >> 2;
  const int sg = (tid & 3) ^ ((sml >> 1) & 3);

  const int isbf = *flag;
  const bf16* Ab = (MODE == 0 && isbf) ? Aalt : A;

  floatx4 acc[4][4] = {};

  for (int k0 = 0; k0 < K; k0 += 32) {
    __syncthreads();
    const bf16* a0 = Ab + (size_t)(bm + sml) * K + k0 + sg * 8;
    gload_lds16(a0, &As[tid * 8]);
    gload_lds16(a0 + (size_t)64 * K, &As[2048 + tid * 8]);
    const bf16* b0 = Bt + (size_t)(bn + sml) * K + k0 + sg * 8;
    gload_lds16(b0, &Bs[tid * 8]);
    gload_lds16(b0 + (size_t)64 * K, &Bs[2048 + tid * 8]);
    __syncthreads();

    short8 af[4], bfr[4];
#pragma unroll
    for (int mi = 0; mi < 4; mi++) {
      int m = wm * 64 + mi * 16 + l15;
      af[mi] = *(const short8*)&As[m * 32 + ((quad ^ ((m >> 1) & 3)) * 8)];
    }
#pragma unroll
    for (int ni = 0; ni < 4; ni++) {
      int n = wn * 64 + ni * 16 + l15;
      bfr[ni] = *(const short8*)&Bs[n * 32 + ((quad ^ ((n >> 1) & 3)) * 8)];
    }
#pragma unroll
    for (int mi = 0; mi < 4; mi++)
#pragma unroll
      for (int ni = 0; ni < 4; ni++)
        acc[mi][ni] = MFMA_BF16(af[mi], bfr[ni], acc[mi][ni]);
  }

#pragma unroll
  for (int mi = 0; mi < 4; mi++) {
    const int row0 = bm + wm * 64 + mi * 16 + quad * 4;
#pragma unroll
    for (int ni = 0; ni < 4; ni++) {
      const int col = bn + wn * 64 + ni * 16 + l15;
      if (MODE == 0) {
        const int sec = col >> 10;
        const int cc = col & 1023;
        const int h = cc >> 6, d = cc & 63;
        const int b_idx = row0 >> 11;
        const int nn0 = row0 & 2047;
        if (sec == 0) {
          bf16* dst = Qo + (size_t)(b_idx * 16 + h) * 131072 + (size_t)nn0 * 64 + d;
#pragma unroll
          for (int r = 0; r < 4; r++) dst[r * 64] = __float2bfloat16(acc[mi][ni][r]);
        } else if (sec == 1) {
          // fold SCALE*log2e*mask_j into K rows; packed-fragment K layout.
          // key = nn0 + r: t,kt fixed (nn0%4==0), l31 = (nn0&31)+r.
          const bf16* mrow = Mk + (size_t)b_idx * 2048 + nn0;
          const int t = nn0 >> 6, kt = (nn0 >> 5) & 1, l31r = nn0 & 31;
          const int g = d >> 3, j = d & 7;
          bf16* dst = Ko + (size_t)(b_idx * 16 + h) * 131072 + t * 4096 + kt * 2048 +
                      (g >> 1) * 512 + (g & 1) * 256 + l31r * 8 + j;
#pragma unroll
          for (int r = 0; r < 4; r++)
            dst[r * 8] = __float2bfloat16(acc[mi][ni][r] * KSCALE *
                                          __bfloat162float(mrow[r]));
        } else {
          // packed-fragment V layout. key = nn0 + r: j = (nn0&7)+r (consecutive,
          // since nn0%4==0 => j0 in {0,4}), all other fields fixed.
          const int t = nn0 >> 6;
          const int kl = nn0 & 63;
          const int g = kl >> 3, j0 = kl & 7;
          bf16* dst = Vo + (size_t)(b_idx * 16 + h) * 131072 + t * 4096 +
                      (d >> 5) * 2048 + (g >> 1) * 512 + (g & 1) * 256 + (d & 31) * 8 + j0;
          ushort4 u;
          u.x = bfbits(acc[mi][ni][0]);
          u.y = bfbits(acc[mi][ni][1]);
          u.z = bfbits(acc[mi][ni][2]);
          u.w = bfbits(acc[mi][ni][3]);
          *(ushort4*)dst = u;
        }
      } else {
        if (isbf) {
          bf16* C2 = (bf16*)Co;
#pragma unroll
          for (int r = 0; r < 4; r++)
            C2[(size_t)(row0 + r) * 1024 + col] = __float2bfloat16(acc[mi][ni][r]);
        } else {
          float* C2 = (float*)Co;
#pragma unroll
          for (int r = 0; r < 4; r++)
            C2[(size_t)(row0 + r) * 1024 + col] = acc[mi][ni][r];
        }
      }
    }
  }
}

// ---------------- flash attention v14 (pipelined, 256-VGPR headroom) ------------
// v12/v13 proved the pipelined schedule (S(t+1) cluster merged with PV(t)) is
// CORRECT but does NOT fit the 128-VGPR cap of (512,4): the allocator split
// 64 arch / 64 acc and spilled the carried floatx16 (1-2 GB/dispatch scratch).
// v14 raises the cap instead of shaving registers: 256-thread blocks (4 waves,
// NO KV-split), __launch_bounds__(256,2) -> 256 VGPR/wave. Each wave sweeps all
// 2048 keys (64 x 32-key iters) for its 32 q-rows; 512 blocks = 2/CU, all
// resident (2 waves/SIMD; r2 measured 4->2 waves/SIMD costs only ~2us).
// Removes the KV-half combine entirely: ZERO LDS, no __syncthreads in flash_k.
// Per iter: [vf loads][kf(it+1) loads][softmax in place on carried sN -> pf
// (T12)][merged 8-MFMA cluster: S(it+1) + 2 PV chains]. Direct-L2 KV
// (fragment-packed 1KB wave loads); XCD swizzle; deferred rsum (one shfl at end).
__global__ __launch_bounds__(256, 2)
void flash_k(const bf16* __restrict__ Q, const bf16* __restrict__ Kp,
             const bf16* __restrict__ Vp, bf16* __restrict__ AO) {
  const int tid = threadIdx.x;
  const int lane = tid & 63;
  const int l31 = lane & 31;
  const int l5h = lane >> 5;  // 0..1
  const int w = tid >> 6;     // 0..3: row group (32 rows each)

  // XCD-aware swizzle (bijective, 512 % 8 == 0): consecutive work units of the
  // same head land on the same XCD -> KV stays in that XCD's L2.
  const int bid = blockIdx.x;
  const int wk = (bid & 7) * 64 + (bid >> 3);
  const int qt = wk & 15;  // 16 tiles x 128 rows
  const int hl = wk >> 4;  // b*16+h
  const int b_idx = hl >> 4, h = hl & 15;

  const bf16* Qh = Q + (size_t)hl * 131072;
  const int lo = l5h * 256 + l31 * 8;  // per-lane elem offset inside a fragment
  const bf16* kptr = Kp + (size_t)hl * 131072 + lo;
  const bf16* vptr = Vp + (size_t)hl * 131072 + lo;

  const int qbase = qt * 128 + w * 32;
  const int qrow = qbase + l31;

  // Q fragments (B-operand of S^T): B[k=d][n=row]: lane n=l31, k=c*16+l5h*8+j
  short8 qf[4];
#pragma unroll
  for (int c = 0; c < 4; c++)
    qf[c] = *(const short8*)&Qh[(size_t)qrow * 64 + c * 16 + l5h * 8];

  floatx16 o_acc[2] = {};  // O^T: col=l31=row, d = dt*32 + (reg&3)+8*(reg>>2)+4*l5h
  float rsm0 = 0.f, rsm1 = 0.f, rsm2 = 0.f, rsm3 = 0.f;  // lane-local partials
  const floatx16 zero16 = {};

  // prologue: sN = S(0); kptr points at the CURRENT 32-key subtile's K
  short8 kf[4];
#pragma unroll
  for (int c = 0; c < 4; c++) kf[c] = *(const short8*)(kptr + c * 512);
  floatx16 sN = zero16;
  __builtin_amdgcn_s_setprio(1);
#pragma unroll
  for (int c = 0; c < 4; c++) sN = MFMA32(kf[c], qf[c], sN);
  __builtin_amdgcn_s_setprio(0);

#pragma unroll 1
  for (int it = 0; it < 64; ++it) {
    const int kv = it & 1;  // which 32-key half of the 64-key packed tile

    // V loads for this tile (consumed in PV below; softmax covers the latency)
    short8 vf[4];
#pragma unroll
    for (int dt = 0; dt < 2; dt++)
#pragma unroll
      for (int ch = 0; ch < 2; ch++)
        vf[dt * 2 + ch] = *(const short8*)(vptr + dt * 2048 + (kv * 2 + ch) * 512);

    // K load for subtile it+1 (consumed by the sN cluster at the end of this iter)
    if (it < 63) {
      kptr += 2048;  // 32-key subtile stride (K packed linearly in key order)
#pragma unroll
      for (int c = 0; c < 4; c++) kf[c] = *(const short8*)(kptr + c * 512);
    }

    // p = exp2(sN) IN PLACE (one score vector live). Lane owns one softmax row
    // (16 of this subtile's 32 keys; other 16 in lane^32 — additive softmax,
    // combined by the single end-of-kernel shfl).
#pragma unroll
    for (int r = 0; r < 16; r += 4) {
      const float p0 = __builtin_amdgcn_exp2f(sN[r + 0]);
      const float p1 = __builtin_amdgcn_exp2f(sN[r + 1]);
      const float p2 = __builtin_amdgcn_exp2f(sN[r + 2]);
      const float p3 = __builtin_amdgcn_exp2f(sN[r + 3]);
      sN[r + 0] = p0; rsm0 += p0;
      sN[r + 1] = p1; rsm1 += p1;
      sN[r + 2] = p2; rsm2 += p2;
      sN[r + 3] = p3; rsm3 += p3;
    }

    // pf[ch][j] = P[key=ch*16+l5h*8+j][row=l31], built in-register (T12).
    // Held: sN[reg] = P[row=l31][key=(reg&3)+8*(reg>>2)+4*l5h].
    short8 pf[2];
#pragma unroll
    for (int ch = 0; ch < 2; ch++) {
      const int rb = ch * 8;
      unsigned x0, x1, y0, y1;
      asm("v_cvt_pk_bf16_f32 %0, %1, %2" : "=v"(x0) : "v"(sN[rb + 0]), "v"(sN[rb + 1]));
      asm("v_cvt_pk_bf16_f32 %0, %1, %2" : "=v"(x1) : "v"(sN[rb + 2]), "v"(sN[rb + 3]));
      asm("v_cvt_pk_bf16_f32 %0, %1, %2" : "=v"(y0) : "v"(sN[rb + 4]), "v"(sN[rb + 5]));
      asm("v_cvt_pk_bf16_f32 %0, %1, %2" : "=v"(y1) : "v"(sN[rb + 6]), "v"(sN[rb + 7]));
      asm("v_permlane32_swap_b32 %0, %1" : "+v"(x0), "+v"(y0));
      asm("v_permlane32_swap_b32 %0, %1" : "+v"(x1), "+v"(y1));
      union { unsigned u[4]; short8 v; } cv;
      cv.u[0] = x0; cv.u[1] = x1; cv.u[2] = y0; cv.u[3] = y1;
      pf[ch] = cv.v;
    }
    // sN is now dead (pf holds P); its registers carry the next S tile.

    // merged MFMA region: S(it+1) (fresh kf) + PV(it) — 3 independent chains
    if (it < 63) {
      sN = zero16;
      __builtin_amdgcn_s_setprio(1);
      sN = MFMA32(kf[0], qf[0], sN);
      o_acc[0] = MFMA32(vf[0], pf[0], o_acc[0]);
      sN = MFMA32(kf[1], qf[1], sN);
      o_acc[1] = MFMA32(vf[2], pf[0], o_acc[1]);
      sN = MFMA32(kf[2], qf[2], sN);
      o_acc[0] = MFMA32(vf[1], pf[1], o_acc[0]);
      sN = MFMA32(kf[3], qf[3], sN);
      o_acc[1] = MFMA32(vf[3], pf[1], o_acc[1]);
      __builtin_amdgcn_s_setprio(0);
    } else {
      __builtin_amdgcn_s_setprio(1);
      o_acc[0] = MFMA32(vf[0], pf[0], o_acc[0]);
      o_acc[1] = MFMA32(vf[2], pf[0], o_acc[1]);
      o_acc[0] = MFMA32(vf[1], pf[1], o_acc[0]);
      o_acc[1] = MFMA32(vf[3], pf[1], o_acc[1]);
      __builtin_amdgcn_s_setprio(0);
    }

    vptr += kv ? 4096 : 0;  // V packed-tile (64-key) stride, advance every 2 iters
  }

  // epilogue: full row-sum (other 16-key half lives in lane^32), then each wave
  // writes its own 32 rows — no combine, no LDS.
  float rsum = (rsm0 + rsm1) + (rsm2 + rsm3);
  rsum += __shfl_xor(rsum, 32, 64);
  const float rinv = 1.f / rsum;
  bf16* orow = AO + (size_t)(b_idx * 2048 + qbase + l31) * 1024 + h * 64;
#pragma unroll
  for (int dt = 0; dt < 2; dt++)
#pragma unroll
    for (int rg2 = 0; rg2 < 4; rg2++) {
      ushort4 u;
      u.x = bfbits(o_acc[dt][rg2 * 4 + 0] * rinv);
      u.y = bfbits(o_acc[dt][rg2 * 4 + 1] * rinv);
      u.z = bfbits(o_acc[dt][rg2 * 4 + 2] * rinv);
      u.w = bfbits(o_acc[dt][rg2 * 4 + 3] * rinv);
      *(ushort4*)&orow[dt * 32 + rg2 * 8 + l5h * 4] = u;
    }
}

extern "C" void kernel_launch(void* const* d_in, const int* in_sizes, int n_in,
                              void* d_out, int out_size, void* d_ws, size_t ws_size,
                              hipStream_t stream) {
  const void* x     = d_in[0];  // [2,2048,1024]  bf16 or fp32 (probed)
  const void* mask  = d_in[1];  // [2,2048]
  const void* w_qkv = d_in[2];  // [1024,3072]
  const void* w_out = d_in[3];  // [1024,1024]

  bf16* ws    = (bf16*)d_ws;
  bf16* xb    = ws;                     // 4194304 (fp32 path only; dead after gemm1)
  bf16* AO    = ws;                     // alias of xb, linear [4096,1024]
  bf16* wqkvT = ws + 4194304;           // 3145728
  bf16* woutT = wqkvT + 3145728;        // 1048576
  bf16* Qb    = woutT + 1048576;        // 4194304
  bf16* Kp    = Qb + 4194304;           // 4194304 (fragment-packed K)
  bf16* maskb = Kp + 4194304;           // 4096
  int*  flag  = (int*)(maskb + 4096);
  bf16* Vp    = (bf16*)d_out;           // 4194304 packed V (dead before gemm2 writes)

  probemask_k<<<1, 256, 0, stream>>>(mask, maskb, flag);
  cvt_k<<<4096, 256, 0, stream>>>(x, xb, 4194304, flag);
  transpose2_k<<<dim3(128, 32), 256, 0, stream>>>(w_qkv, wqkvT, w_out, woutT, flag);
  gemm_k<0><<<dim3(24, 32), 256, 0, stream>>>(xb, (const bf16*)x, wqkvT, Qb, Kp, Vp,
                                              nullptr, maskb, flag);
  flash_k<<<512, 256, 0, stream>>>(Qb, Kp, Vp, AO);
  gemm_k<1><<<dim3(8, 32), 256, 0, stream>>>(AO, nullptr, woutT, nullptr, nullptr,
                                             nullptr, d_out, nullptr, flag);
}

// Round 9
// 188.568 us; speedup vs baseline: 4.4345x; 1.0372x over previous
//
#include <hip/hip_runtime.h>
#include <hip/hip_bf16.h>

using bf16 = __hip_bfloat16;
typedef __attribute__((ext_vector_type(8))) short short8;
typedef __attribute__((ext_vector_type(4))) float floatx4;
typedef __attribute__((ext_vector_type(16))) float floatx16;

#define MFMA_BF16(a, b, c) __builtin_amdgcn_mfma_f32_16x16x32_bf16((a), (b), (c), 0, 0, 0)
#define MFMA32(a, b, c) __builtin_amdgcn_mfma_f32_32x32x16_bf16((a), (b), (c), 0, 0, 0)

__device__ __forceinline__ void gload_lds16(const bf16* g, bf16* l) {
  __builtin_amdgcn_global_load_lds((__attribute__((address_space(1))) void*)g,
                                   (__attribute__((address_space(3))) void*)l,
                                   16, 0, 0);
}

__device__ __forceinline__ unsigned short bfbits(float f) {
  bf16 b = __float2bfloat16(f);
  return *reinterpret_cast<unsigned short*>(&b);
}

// K-scale: SCALE * log2(e) folded so flash uses raw v_exp_f32 (=exp2)
#define KSCALE 0.18033688011112042f

// ---------- probe dtype (seq_mask words are {0,0x3F800000} iff fp32) + cvt mask ----
__global__ __launch_bounds__(256)
void probemask_k(const void* __restrict__ msrc, bf16* __restrict__ dst,
                 int* __restrict__ flag) {
  __shared__ int any;
  const int tid = threadIdx.x;
  if (tid == 0) any = 0;
  __syncthreads();
  const unsigned* mw = (const unsigned*)msrc;
  int bad = 0;
#pragma unroll
  for (int i = 0; i < 4; i++) {
    unsigned w = mw[tid * 4 + i];
    if (w != 0u && w != 0x3F800000u) bad = 1;
  }
  if (bad) atomicOr(&any, 1);
  __syncthreads();
  const int isbf = any;  // 1 => inputs bf16, 0 => fp32
  if (tid == 0) flag[0] = isbf;
  if (isbf) {
#pragma unroll
    for (int i = 0; i < 2; i++)
      ((int4*)dst)[tid * 2 + i] = ((const int4*)msrc)[tid * 2 + i];
  } else {
#pragma unroll
    for (int i = 0; i < 4; i++) {
      float4 v = ((const float4*)msrc)[tid * 4 + i];
      int o = tid * 16 + i * 4;
      dst[o + 0] = __float2bfloat16(v.x);
      dst[o + 1] = __float2bfloat16(v.y);
      dst[o + 2] = __float2bfloat16(v.z);
      dst[o + 3] = __float2bfloat16(v.w);
    }
  }
}

// ---------- fused prep: cvt x (fp32 path) + both weight transposes ---------------
// grid 8192: blocks <4096 do cvt (fp32->bf16 of x), >=4096 do the 32x32 transpose
// tiles of w_qkv/w_out. One launch instead of two (launch-gap cut).
__global__ __launch_bounds__(256)
void prep_k(const void* __restrict__ xsrc, bf16* __restrict__ xb,
            const void* __restrict__ in0, bf16* __restrict__ out0,
            const void* __restrict__ in1, bf16* __restrict__ out1,
            const int* __restrict__ flag) {
  __shared__ bf16 tile[32][33];
  const int isbf = *flag;
  if (blockIdx.x < 4096) {
    if (isbf) return;  // bf16 path: gemm reads x directly
    int i = (blockIdx.x * 256 + threadIdx.x) * 4;
    float4 v = ((const float4*)xsrc)[i >> 2];
    xb[i + 0] = __float2bfloat16(v.x);
    xb[i + 1] = __float2bfloat16(v.y);
    xb[i + 2] = __float2bfloat16(v.z);
    xb[i + 3] = __float2bfloat16(v.w);
    return;
  }
  constexpr int R = 1024;
  const int t = blockIdx.x - 4096;
  const int bxi = t & 127;      // original blockIdx.x of transpose2
  const int by = (t >> 7) * 32; // original blockIdx.y*32
  const void* in;
  bf16* out;
  int C, bx;
  if (bxi < 96) { in = in0; out = out0; C = 3072; bx = bxi * 32; }
  else          { in = in1; out = out1; C = 1024; bx = (bxi - 96) * 32; }
  int tx = threadIdx.x & 31, ty = threadIdx.x >> 5;
#pragma unroll
  for (int i = 0; i < 4; i++) {
    size_t idx = (size_t)(by + ty + i * 8) * C + bx + tx;
    tile[ty + i * 8][tx] =
        isbf ? ((const bf16*)in)[idx] : __float2bfloat16(((const float*)in)[idx]);
  }
  __syncthreads();
#pragma unroll
  for (int i = 0; i < 4; i++)
    out[(size_t)(bx + ty + i * 8) * R + by + tx] = tile[tx][ty + i * 8];
}

// ---------------- GEMM: C[M,N] = A[M,1024] @ Bt[N,1024]^T ----------------
// 128x128 tiles. MODE 0: A = x [4096,1024], N=3072; scatters Q->[b,h,n,d],
// K and V in FRAGMENT-PACKED layouts (consumed by flash_k as wave-contiguous
// 1KB coalesced loads): packed elem (tile t=key>>6, half, c, gh, l31, j) at
// t*4096 + half*2048 + c*512 + gh*256 + l31*8 + j.
//   K: half=kt=(key>>5)&1, l31=key&31, d=(c*2+gh)*8+j  (pre-scaled KSCALE*mask)
//   V: half=dt=d>>5,       l31=d&31,   key_local=(c*2+gh)*8+j
// MODE 1: A = AO [4096,1024] (linear), N=1024 -> Co (bf16/f32 per flag).
// XCD-aware bijective swizzle (T1): consecutive dispatch ids (round-robin to
// XCDs) get work ids one chunk apart -> each XCD keeps reusing one A-row panel
// in its private L2. nwg = 768 (MODE0) / 256 (MODE1), both % 8 == 0.
template <int MODE>
__global__ __launch_bounds__(256, 2)
void gemm_k(const bf16* __restrict__ A, const bf16* __restrict__ Aalt,
            const bf16* __restrict__ Bt,
            bf16* __restrict__ Qo, bf16* __restrict__ Ko, bf16* __restrict__ Vo,
            void* __restrict__ Co, const bf16* __restrict__ Mk,
            const int* __restrict__ flag) {
  constexpr int K = 1024;
  __shared__ __align__(16) bf16 As[128 * 32];
  __shared__ __align__(16) bf16 Bs[128 * 32];

  const int tid = threadIdx.x;
  const int lane = tid & 63;
  const int wv = tid >> 6;
  const int wm = wv & 1, wn = wv >> 1;
  const int l15 = lane & 15, quad = lane >> 4;

  const int nbx = gridDim.x;
  const int nwg = nbx * gridDim.y;
  int wid = blockIdx.y * nbx + blockIdx.x;
  wid = (wid & 7) * (nwg >> 3) + (wid >> 3);
  const int bm = (wid / nbx) * 128;
  const int bn = (wid % nbx) * 128;

  const int sml = tid >> 2;
  const int sg = (tid & 3) ^ ((sml >> 1) & 3);

  const int isbf = *flag;
  const bf16* Ab = (MODE == 0 && isbf) ? Aalt : A;

  floatx4 acc[4][4] = {};

  for (int k0 = 0; k0 < K; k0 += 32) {
    __syncthreads();
    const bf16* a0 = Ab + (size_t)(bm + sml) * K + k0 + sg * 8;
    gload_lds16(a0, &As[tid * 8]);
    gload_lds16(a0 + (size_t)64 * K, &As[2048 + tid * 8]);
    const bf16* b0 = Bt + (size_t)(bn + sml) * K + k0 + sg * 8;
    gload_lds16(b0, &Bs[tid * 8]);
    gload_lds16(b0 + (size_t)64 * K, &Bs[2048 + tid * 8]);
    __syncthreads();

    short8 af[4], bfr[4];
#pragma unroll
    for (int mi = 0; mi < 4; mi++) {
      int m = wm * 64 + mi * 16 + l15;
      af[mi] = *(const short8*)&As[m * 32 + ((quad ^ ((m >> 1) & 3)) * 8)];
    }
#pragma unroll
    for (int ni = 0; ni < 4; ni++) {
      int n = wn * 64 + ni * 16 + l15;
      bfr[ni] = *(const short8*)&Bs[n * 32 + ((quad ^ ((n >> 1) & 3)) * 8)];
    }
#pragma unroll
    for (int mi = 0; mi < 4; mi++)
#pragma unroll
      for (int ni = 0; ni < 4; ni++)
        acc[mi][ni] = MFMA_BF16(af[mi], bfr[ni], acc[mi][ni]);
  }

#pragma unroll
  for (int mi = 0; mi < 4; mi++) {
    const int row0 = bm + wm * 64 + mi * 16 + quad * 4;
#pragma unroll
    for (int ni = 0; ni < 4; ni++) {
      const int col = bn + wn * 64 + ni * 16 + l15;
      if (MODE == 0) {
        const int sec = col >> 10;
        const int cc = col & 1023;
        const int h = cc >> 6, d = cc & 63;
        const int b_idx = row0 >> 11;
        const int nn0 = row0 & 2047;
        if (sec == 0) {
          bf16* dst = Qo + (size_t)(b_idx * 16 + h) * 131072 + (size_t)nn0 * 64 + d;
#pragma unroll
          for (int r = 0; r < 4; r++) dst[r * 64] = __float2bfloat16(acc[mi][ni][r]);
        } else if (sec == 1) {
          // fold SCALE*log2e*mask_j into K rows; packed-fragment K layout.
          // key = nn0 + r: t,kt fixed (nn0%4==0), l31 = (nn0&31)+r.
          const bf16* mrow = Mk + (size_t)b_idx * 2048 + nn0;
          const int t = nn0 >> 6, kt = (nn0 >> 5) & 1, l31r = nn0 & 31;
          const int g = d >> 3, j = d & 7;
          bf16* dst = Ko + (size_t)(b_idx * 16 + h) * 131072 + t * 4096 + kt * 2048 +
                      (g >> 1) * 512 + (g & 1) * 256 + l31r * 8 + j;
#pragma unroll
          for (int r = 0; r < 4; r++)
            dst[r * 8] = __float2bfloat16(acc[mi][ni][r] * KSCALE *
                                          __bfloat162float(mrow[r]));
        } else {
          // packed-fragment V layout. key = nn0 + r: j = (nn0&7)+r (consecutive,
          // since nn0%4==0 => j0 in {0,4}), all other fields fixed.
          const int t = nn0 >> 6;
          const int kl = nn0 & 63;
          const int g = kl >> 3, j0 = kl & 7;
          bf16* dst = Vo + (size_t)(b_idx * 16 + h) * 131072 + t * 4096 +
                      (d >> 5) * 2048 + (g >> 1) * 512 + (g & 1) * 256 + (d & 31) * 8 + j0;
          ushort4 u;
          u.x = bfbits(acc[mi][ni][0]);
          u.y = bfbits(acc[mi][ni][1]);
          u.z = bfbits(acc[mi][ni][2]);
          u.w = bfbits(acc[mi][ni][3]);
          *(ushort4*)dst = u;
        }
      } else {
        if (isbf) {
          bf16* C2 = (bf16*)Co;
#pragma unroll
          for (int r = 0; r < 4; r++)
            C2[(size_t)(row0 + r) * 1024 + col] = __float2bfloat16(acc[mi][ni][r]);
        } else {
          float* C2 = (float*)Co;
#pragma unroll
          for (int r = 0; r < 4; r++)
            C2[(size_t)(row0 + r) * 1024 + col] = acc[mi][ni][r];
        }
      }
    }
  }
}

// ---------------- flash attention v15 (= v10b + VALU-traffic cuts) --------------
// v10b (r4, PASSED, 49.8us) is the best measured cell of the {staging}x{pipe}x
// {waves} grid; v14 falsified the pipelining theory (56us spill-free at 2
// waves/SIMD, VALUBusy 47% = accvgpr-move overhead dominating). v15 keeps
// v10b's structure (4 waves/SIMD, direct-L2 fragment-packed KV, KV-split
// halves, no main-loop barriers) and cuts only VALU register traffic:
//  (a) exp2 results go to fresh scalar regs feeding cvt_pk — NO write-back
//      into the AGPR-resident score vector (saves ~32 accvgpr moves/iter);
//  (b) deferred rsum: lane-local partials, ONE shfl_xor at the end instead of
//      32 (exactness proven by v14's passing run).
__global__ __launch_bounds__(512, 4)
void flash_k(const bf16* __restrict__ Q, const bf16* __restrict__ Kp,
             const bf16* __restrict__ Vp, bf16* __restrict__ AO) {
  __shared__ __align__(16) float cb[4 * 64 * 32];  // 32 KB combine buffer
  __shared__ float rbuf[4 * 64];                   // 1 KB rsum combine

  const int tid = threadIdx.x;
  const int lane = tid & 63;
  const int l31 = lane & 31;
  const int l5h = lane >> 5;  // 0..1
  const int w = tid >> 6;     // 0..7
  const int rg = w & 3;       // row group (32 rows each)
  const int half = w >> 2;    // KV half: 0 -> keys 0..1023, 1 -> 1024..2047

  // XCD-aware swizzle (bijective, 512 % 8 == 0): consecutive work units of the
  // same head land on the same XCD -> KV stays in that XCD's L2.
  const int bid = blockIdx.x;
  const int wk = (bid & 7) * 64 + (bid >> 3);
  const int qt = wk & 15;  // 16 tiles x 128 rows
  const int hl = wk >> 4;  // b*16+h
  const int b_idx = hl >> 4, h = hl & 15;

  const bf16* Qh = Q + (size_t)hl * 131072;
  const int lo = l5h * 256 + l31 * 8;  // per-lane elem offset inside a fragment
  const bf16* kptr = Kp + (size_t)hl * 131072 + (size_t)(half * 16) * 4096 + lo;
  const bf16* vptr = Vp + (size_t)hl * 131072 + (size_t)(half * 16) * 4096 + lo;

  const int qbase = qt * 128 + rg * 32;
  const int qrow = qbase + l31;

  // Q fragments (B-operand of S^T): B[k=d][n=row]: lane n=l31, k=c*16+l5h*8+j
  short8 qf[4];
#pragma unroll
  for (int c = 0; c < 4; c++)
    qf[c] = *(const short8*)&Qh[(size_t)qrow * 64 + c * 16 + l5h * 8];

  floatx16 o_acc[2] = {};  // O^T: col=l31=row, d = dt*32 + (reg&3)+8*(reg>>2)+4*l5h
  float rsm0 = 0.f, rsm1 = 0.f, rsm2 = 0.f, rsm3 = 0.f;  // lane-local partials

  // preload K fragments of 32-key tile 0 (K packed: 32-key subtile stride 2048)
  short8 kf[4];
#pragma unroll
  for (int c = 0; c < 4; c++) kf[c] = *(const short8*)(kptr + c * 512);

#pragma unroll 1
  for (int it = 0; it < 32; ++it) {
    const int kv = it & 1;  // which 32-key half of the 64-key packed tile

    // S^T = K' Q^T : A = K'[key][d]: lane row=key=l31, k=l5h*8+j per c-chunk
    floatx16 s = {};
    __builtin_amdgcn_s_setprio(1);
#pragma unroll
    for (int c = 0; c < 4; c++) s = MFMA32(kf[c], qf[c], s);
    __builtin_amdgcn_s_setprio(0);

    // V loads for this tile, issued FIRST (consumed in PV this iter; in-order
    // vmcnt => PV's wait doesn't drain the K prefetch behind them)
    short8 vf[4];
#pragma unroll
    for (int dt = 0; dt < 2; dt++)
#pragma unroll
      for (int ch = 0; ch < 2; ch++)
        vf[dt * 2 + ch] = *(const short8*)(vptr + dt * 2048 + (kv * 2 + ch) * 512);

    // prefetch K fragments of next tile (kf dead after S-MFMAs; lands ~next S)
    kptr += (it < 31) ? 2048 : 0;
#pragma unroll
    for (int c = 0; c < 4; c++) kf[c] = *(const short8*)(kptr + c * 512);

    // p = exp2(s) into FRESH scalars (no write-back into the AGPR-resident s);
    // lane owns one softmax row (16 of this tile's 32 keys; other 16 in
    // lane^32 — additive softmax, combined once at the end).
    float e[16];
#pragma unroll
    for (int r = 0; r < 16; r += 4) {
      e[r + 0] = __builtin_amdgcn_exp2f(s[r + 0]);
      e[r + 1] = __builtin_amdgcn_exp2f(s[r + 1]);
      e[r + 2] = __builtin_amdgcn_exp2f(s[r + 2]);
      e[r + 3] = __builtin_amdgcn_exp2f(s[r + 3]);
      rsm0 += e[r + 0];
      rsm1 += e[r + 1];
      rsm2 += e[r + 2];
      rsm3 += e[r + 3];
    }

    // pf[ch][j] = P[key=ch*16+l5h*8+j][row=l31], built in-register (T12).
    // Held: e[reg] = P[row=l31][key=(reg&3)+8*(reg>>2)+4*l5h].
    short8 pf[2];
#pragma unroll
    for (int ch = 0; ch < 2; ch++) {
      const int rb = ch * 8;
      unsigned x0, x1, y0, y1;
      asm("v_cvt_pk_bf16_f32 %0, %1, %2" : "=v"(x0) : "v"(e[rb + 0]), "v"(e[rb + 1]));
      asm("v_cvt_pk_bf16_f32 %0, %1, %2" : "=v"(x1) : "v"(e[rb + 2]), "v"(e[rb + 3]));
      asm("v_cvt_pk_bf16_f32 %0, %1, %2" : "=v"(y0) : "v"(e[rb + 4]), "v"(e[rb + 5]));
      asm("v_cvt_pk_bf16_f32 %0, %1, %2" : "=v"(y1) : "v"(e[rb + 6]), "v"(e[rb + 7]));
      asm("v_permlane32_swap_b32 %0, %1" : "+v"(x0), "+v"(y0));
      asm("v_permlane32_swap_b32 %0, %1" : "+v"(x1), "+v"(y1));
      union { unsigned u[4]; short8 v; } cv;
      cv.u[0] = x0; cv.u[1] = x1; cv.u[2] = y0; cv.u[3] = y1;
      pf[ch] = cv.v;
    }

    // O^T += V^T P^T : A = V^T[d][key]: lane row=d=dt*32+l31 (per dt)
    __builtin_amdgcn_s_setprio(1);
#pragma unroll
    for (int dt = 0; dt < 2; dt++)
#pragma unroll
      for (int ch = 0; ch < 2; ch++)
        o_acc[dt] = MFMA32(vf[dt * 2 + ch], pf[ch], o_acc[dt]);
    __builtin_amdgcn_s_setprio(0);

    vptr += kv ? 4096 : 0;  // V packed-tile (64-key) stride, advance every 2 iters
  }

  // deferred rsum: one cross-half-of-wave shfl for this wave's 1024 keys
  float rsum = (rsm0 + rsm1) + (rsm2 + rsm3);
  rsum += __shfl_xor(rsum, 32, 64);

  // ---- combine KV halves: waves 4-7 hand o_acc/rsum to partner via LDS ----
  if (w >= 4) {
    const int slot = (w - 4) * 64 + lane;
    float4* dst = (float4*)(cb + (size_t)slot * 32);
#pragma unroll
    for (int dt = 0; dt < 2; dt++)
#pragma unroll
      for (int q = 0; q < 4; q++) {
        float4 v = make_float4(o_acc[dt][q * 4 + 0], o_acc[dt][q * 4 + 1],
                               o_acc[dt][q * 4 + 2], o_acc[dt][q * 4 + 3]);
        dst[(dt * 4 + q) ^ (lane & 7)] = v;  // xor-swizzle: conflict-free
      }
    rbuf[slot] = rsum;
  }
  __syncthreads();
  if (w < 4) {
    const int slot = w * 64 + lane;
    const float4* src = (const float4*)(cb + (size_t)slot * 32);
#pragma unroll
    for (int dt = 0; dt < 2; dt++)
#pragma unroll
      for (int q = 0; q < 4; q++) {
        float4 v = src[(dt * 4 + q) ^ (lane & 7)];
        o_acc[dt][q * 4 + 0] += v.x;
        o_acc[dt][q * 4 + 1] += v.y;
        o_acc[dt][q * 4 + 2] += v.z;
        o_acc[dt][q * 4 + 3] += v.w;
      }
    rsum += rbuf[slot];

    // epilogue: lane owns q-row qbase+l31; AO linear [b*2048+n][1024], col=h*64+d
    const float rinv = 1.f / rsum;
    bf16* orow = AO + (size_t)(b_idx * 2048 + qbase + l31) * 1024 + h * 64;
#pragma unroll
    for (int dt = 0; dt < 2; dt++)
#pragma unroll
      for (int rg2 = 0; rg2 < 4; rg2++) {
        ushort4 u;
        u.x = bfbits(o_acc[dt][rg2 * 4 + 0] * rinv);
        u.y = bfbits(o_acc[dt][rg2 * 4 + 1] * rinv);
        u.z = bfbits(o_acc[dt][rg2 * 4 + 2] * rinv);
        u.w = bfbits(o_acc[dt][rg2 * 4 + 3] * rinv);
        *(ushort4*)&orow[dt * 32 + rg2 * 8 + l5h * 4] = u;
      }
  }
}

extern "C" void kernel_launch(void* const* d_in, const int* in_sizes, int n_in,
                              void* d_out, int out_size, void* d_ws, size_t ws_size,
                              hipStream_t stream) {
  const void* x     = d_in[0];  // [2,2048,1024]  bf16 or fp32 (probed)
  const void* mask  = d_in[1];  // [2,2048]
  const void* w_qkv = d_in[2];  // [1024,3072]
  const void* w_out = d_in[3];  // [1024,1024]

  bf16* ws    = (bf16*)d_ws;
  bf16* xb    = ws;                     // 4194304 (fp32 path only; dead after gemm1)
  bf16* AO    = ws;                     // alias of xb, linear [4096,1024]
  bf16* wqkvT = ws + 4194304;           // 3145728
  bf16* woutT = wqkvT + 3145728;        // 1048576
  bf16* Qb    = woutT + 1048576;        // 4194304
  bf16* Kp    = Qb + 4194304;           // 4194304 (fragment-packed K)
  bf16* maskb = Kp + 4194304;           // 4096
  int*  flag  = (int*)(maskb + 4096);
  bf16* Vp    = (bf16*)d_out;           // 4194304 packed V (dead before gemm2 writes)

  probemask_k<<<1, 256, 0, stream>>>(mask, maskb, flag);
  prep_k<<<8192, 256, 0, stream>>>(x, xb, w_qkv, wqkvT, w_out, woutT, flag);
  gemm_k<0><<<dim3(24, 32), 256, 0, stream>>>(xb, (const bf16*)x, wqkvT, Qb, Kp, Vp,
                                              nullptr, maskb, flag);
  flash_k<<<512, 512, 0, stream>>>(Qb, Kp, Vp, AO);
  gemm_k<1><<<dim3(8, 32), 256, 0, stream>>>(AO, nullptr, woutT, nullptr, nullptr,
                                             nullptr, d_out, nullptr, flag);
}

// Round 10
// 182.660 us; speedup vs baseline: 4.5779x; 1.0323x over previous
//
#include <hip/hip_runtime.h>
#include <hip/hip_bf16.h>

using bf16 = __hip_bfloat16;
typedef __attribute__((ext_vector_type(8))) short short8;
typedef __attribute__((ext_vector_type(4))) float floatx4;
typedef __attribute__((ext_vector_type(16))) float floatx16;

#define MFMA_BF16(a, b, c) __builtin_amdgcn_mfma_f32_16x16x32_bf16((a), (b), (c), 0, 0, 0)
#define MFMA32(a, b, c) __builtin_amdgcn_mfma_f32_32x32x16_bf16((a), (b), (c), 0, 0, 0)

__device__ __forceinline__ void gload_lds16(const bf16* g, bf16* l) {
  __builtin_amdgcn_global_load_lds((__attribute__((address_space(1))) void*)g,
                                   (__attribute__((address_space(3))) void*)l,
                                   16, 0, 0);
}

__device__ __forceinline__ unsigned short bfbits(float f) {
  bf16 b = __float2bfloat16(f);
  return *reinterpret_cast<unsigned short*>(&b);
}

// K-scale: SCALE * log2(e) folded so flash uses raw v_exp_f32 (=exp2)
#define KSCALE 0.18033688011112042f

// ---------- fused prep: dtype probe + cvt x + weight transposes + mask cvt ------
// grid 8193. EVERY block computes isbf locally from the mask words (16KB,
// L2-cached; words are {0,0x3F800000} iff fp32 — same test probemask_k used).
// Blocks <4096: cvt x (fp32 path). 4096..8191: 32x32 transpose tiles of
// w_qkv/w_out. Block 8192: writes flag + maskb for the gemms. Removes the
// serial probemask_k launch entirely.
__global__ __launch_bounds__(256)
void prep_k(const void* __restrict__ msrc, bf16* __restrict__ maskb,
            int* __restrict__ flag,
            const void* __restrict__ xsrc, bf16* __restrict__ xb,
            const void* __restrict__ in0, bf16* __restrict__ out0,
            const void* __restrict__ in1, bf16* __restrict__ out1) {
  __shared__ int any;
  __shared__ bf16 tile[32][33];
  const int tid = threadIdx.x;
  if (tid == 0) any = 0;
  __syncthreads();
  const unsigned* mw = (const unsigned*)msrc;
  int bad = 0;
#pragma unroll
  for (int i = 0; i < 4; i++) {
    unsigned w_ = mw[tid * 4 + i];
    if (w_ != 0u && w_ != 0x3F800000u) bad = 1;
  }
  if (bad) atomicOr(&any, 1);
  __syncthreads();
  const int isbf = any;  // 1 => inputs bf16, 0 => fp32

  if (blockIdx.x == 8192) {  // flag + maskb producer
    if (tid == 0) flag[0] = isbf;
    if (isbf) {
#pragma unroll
      for (int i = 0; i < 2; i++)
        ((int4*)maskb)[tid * 2 + i] = ((const int4*)msrc)[tid * 2 + i];
    } else {
#pragma unroll
      for (int i = 0; i < 4; i++) {
        float4 v = ((const float4*)msrc)[tid * 4 + i];
        int o = tid * 16 + i * 4;
        maskb[o + 0] = __float2bfloat16(v.x);
        maskb[o + 1] = __float2bfloat16(v.y);
        maskb[o + 2] = __float2bfloat16(v.z);
        maskb[o + 3] = __float2bfloat16(v.w);
      }
    }
    return;
  }

  if (blockIdx.x < 4096) {  // x cvt (fp32 path only; bf16 path reads x directly)
    if (isbf) return;
    int i = (blockIdx.x * 256 + tid) * 4;
    float4 v = ((const float4*)xsrc)[i >> 2];
    xb[i + 0] = __float2bfloat16(v.x);
    xb[i + 1] = __float2bfloat16(v.y);
    xb[i + 2] = __float2bfloat16(v.z);
    xb[i + 3] = __float2bfloat16(v.w);
    return;
  }

  constexpr int R = 1024;
  const int t = blockIdx.x - 4096;
  const int bxi = t & 127;       // original transpose blockIdx.x
  const int by = (t >> 7) * 32;  // original blockIdx.y*32
  const void* in;
  bf16* out;
  int C, bx;
  if (bxi < 96) { in = in0; out = out0; C = 3072; bx = bxi * 32; }
  else          { in = in1; out = out1; C = 1024; bx = (bxi - 96) * 32; }
  int tx = tid & 31, ty = tid >> 5;
#pragma unroll
  for (int i = 0; i < 4; i++) {
    size_t idx = (size_t)(by + ty + i * 8) * C + bx + tx;
    tile[ty + i * 8][tx] =
        isbf ? ((const bf16*)in)[idx] : __float2bfloat16(((const float*)in)[idx]);
  }
  __syncthreads();
#pragma unroll
  for (int i = 0; i < 4; i++)
    out[(size_t)(bx + ty + i * 8) * R + by + tx] = tile[tx][ty + i * 8];
}

// ---------------- GEMM: C[M,N] = A[M,1024] @ Bt[N,1024]^T ----------------
// 128x128 tiles, BK=64: each iteration stages TWO verbatim copies of the proven
// 128x32 tile (half 0: cols k0..k0+31 at LDS base 0, half 1: k0+32.. at 4096)
// and runs 2x16 MFMAs per barrier pair -> half the vmcnt(0)-drain barriers of
// BK=32 (the m97-structure's ~20% stall). LDS 32KB (2-4 blocks/CU).
// MODE 0: A = x [4096,1024], N=3072; scatters Q->[b,h,n,d], K and V in
// FRAGMENT-PACKED layouts (flash_k reads each MFMA fragment as one
// wave-contiguous 1KB load): packed elem (t=key>>6, half, c, gh, l31, j) at
// t*4096 + half*2048 + c*512 + gh*256 + l31*8 + j.
//   K: half=kt=(key>>5)&1, l31=key&31, d=(c*2+gh)*8+j  (pre-scaled KSCALE*mask)
//   V: half=dt=d>>5,       l31=d&31,   key_local=(c*2+gh)*8+j
// MODE 1: A = AO [4096,1024] (linear), N=1024 -> Co (bf16/f32 per flag).
// XCD-aware bijective swizzle (T1): nwg = 768 / 256, both % 8 == 0.
template <int MODE>
__global__ __launch_bounds__(256, 2)
void gemm_k(const bf16* __restrict__ A, const bf16* __restrict__ Aalt,
            const bf16* __restrict__ Bt,
            bf16* __restrict__ Qo, bf16* __restrict__ Ko, bf16* __restrict__ Vo,
            void* __restrict__ Co, const bf16* __restrict__ Mk,
            const int* __restrict__ flag) {
  constexpr int K = 1024;
  __shared__ __align__(16) bf16 As[128 * 64];  // two 128x32 halves (0 / +4096)
  __shared__ __align__(16) bf16 Bs[128 * 64];

  const int tid = threadIdx.x;
  const int lane = tid & 63;
  const int wv = tid >> 6;
  const int wm = wv & 1, wn = wv >> 1;
  const int l15 = lane & 15, quad = lane >> 4;

  const int nbx = gridDim.x;
  const int nwg = nbx * gridDim.y;
  int wid = blockIdx.y * nbx + blockIdx.x;
  wid = (wid & 7) * (nwg >> 3) + (wid >> 3);
  const int bm = (wid / nbx) * 128;
  const int bn = (wid % nbx) * 128;

  const int sml = tid >> 2;
  const int sg = (tid & 3) ^ ((sml >> 1) & 3);

  const int isbf = *flag;
  const bf16* Ab = (MODE == 0 && isbf) ? Aalt : A;

  floatx4 acc[4][4] = {};

  for (int k0 = 0; k0 < K; k0 += 64) {
    __syncthreads();
#pragma unroll
    for (int hf = 0; hf < 2; hf++) {
      const bf16* a0 = Ab + (size_t)(bm + sml) * K + k0 + hf * 32 + sg * 8;
      gload_lds16(a0, &As[hf * 4096 + tid * 8]);
      gload_lds16(a0 + (size_t)64 * K, &As[hf * 4096 + 2048 + tid * 8]);
      const bf16* b0 = Bt + (size_t)(bn + sml) * K + k0 + hf * 32 + sg * 8;
      gload_lds16(b0, &Bs[hf * 4096 + tid * 8]);
      gload_lds16(b0 + (size_t)64 * K, &Bs[hf * 4096 + 2048 + tid * 8]);
    }
    __syncthreads();

#pragma unroll
    for (int hf = 0; hf < 2; hf++) {
      const bf16* Ah = &As[hf * 4096];
      const bf16* Bh = &Bs[hf * 4096];
      short8 af[4], bfr[4];
#pragma unroll
      for (int mi = 0; mi < 4; mi++) {
        int m = wm * 64 + mi * 16 + l15;
        af[mi] = *(const short8*)&Ah[m * 32 + ((quad ^ ((m >> 1) & 3)) * 8)];
      }
#pragma unroll
      for (int ni = 0; ni < 4; ni++) {
        int n = wn * 64 + ni * 16 + l15;
        bfr[ni] = *(const short8*)&Bh[n * 32 + ((quad ^ ((n >> 1) & 3)) * 8)];
      }
#pragma unroll
      for (int mi = 0; mi < 4; mi++)
#pragma unroll
        for (int ni = 0; ni < 4; ni++)
          acc[mi][ni] = MFMA_BF16(af[mi], bfr[ni], acc[mi][ni]);
    }
  }

#pragma unroll
  for (int mi = 0; mi < 4; mi++) {
    const int row0 = bm + wm * 64 + mi * 16 + quad * 4;
#pragma unroll
    for (int ni = 0; ni < 4; ni++) {
      const int col = bn + wn * 64 + ni * 16 + l15;
      if (MODE == 0) {
        const int sec = col >> 10;
        const int cc = col & 1023;
        const int h = cc >> 6, d = cc & 63;
        const int b_idx = row0 >> 11;
        const int nn0 = row0 & 2047;
        if (sec == 0) {
          bf16* dst = Qo + (size_t)(b_idx * 16 + h) * 131072 + (size_t)nn0 * 64 + d;
#pragma unroll
          for (int r = 0; r < 4; r++) dst[r * 64] = __float2bfloat16(acc[mi][ni][r]);
        } else if (sec == 1) {
          // fold SCALE*log2e*mask_j into K rows; packed-fragment K layout.
          // key = nn0 + r: t,kt fixed (nn0%4==0), l31 = (nn0&31)+r.
          const bf16* mrow = Mk + (size_t)b_idx * 2048 + nn0;
          const int t = nn0 >> 6, kt = (nn0 >> 5) & 1, l31r = nn0 & 31;
          const int g = d >> 3, j = d & 7;
          bf16* dst = Ko + (size_t)(b_idx * 16 + h) * 131072 + t * 4096 + kt * 2048 +
                      (g >> 1) * 512 + (g & 1) * 256 + l31r * 8 + j;
#pragma unroll
          for (int r = 0; r < 4; r++)
            dst[r * 8] = __float2bfloat16(acc[mi][ni][r] * KSCALE *
                                          __bfloat162float(mrow[r]));
        } else {
          // packed-fragment V layout. key = nn0 + r: j = (nn0&7)+r (consecutive,
          // since nn0%4==0 => j0 in {0,4}), all other fields fixed.
          const int t = nn0 >> 6;
          const int kl = nn0 & 63;
          const int g = kl >> 3, j0 = kl & 7;
          bf16* dst = Vo + (size_t)(b_idx * 16 + h) * 131072 + t * 4096 +
                      (d >> 5) * 2048 + (g >> 1) * 512 + (g & 1) * 256 + (d & 31) * 8 + j0;
          ushort4 u;
          u.x = bfbits(acc[mi][ni][0]);
          u.y = bfbits(acc[mi][ni][1]);
          u.z = bfbits(acc[mi][ni][2]);
          u.w = bfbits(acc[mi][ni][3]);
          *(ushort4*)dst = u;
        }
      } else {
        if (isbf) {
          bf16* C2 = (bf16*)Co;
#pragma unroll
          for (int r = 0; r < 4; r++)
            C2[(size_t)(row0 + r) * 1024 + col] = __float2bfloat16(acc[mi][ni][r]);
        } else {
          float* C2 = (float*)Co;
#pragma unroll
          for (int r = 0; r < 4; r++)
            C2[(size_t)(row0 + r) * 1024 + col] = acc[mi][ni][r];
        }
      }
    }
  }
}

// ---------------- flash attention v15 (UNCHANGED from r9: 49.8us, stable) -------
// Best measured cell of {staging}x{pipelining}x{waves}: 4 waves/SIMD, direct-L2
// fragment-packed KV, KV-split halves, no main-loop barriers. exp2 to fresh
// scalars (no AGPR write-back); deferred rsum (one shfl at end).
__global__ __launch_bounds__(512, 4)
void flash_k(const bf16* __restrict__ Q, const bf16* __restrict__ Kp,
             const bf16* __restrict__ Vp, bf16* __restrict__ AO) {
  __shared__ __align__(16) float cb[4 * 64 * 32];  // 32 KB combine buffer
  __shared__ float rbuf[4 * 64];                   // 1 KB rsum combine

  const int tid = threadIdx.x;
  const int lane = tid & 63;
  const int l31 = lane & 31;
  const int l5h = lane >> 5;  // 0..1
  const int w = tid >> 6;     // 0..7
  const int rg = w & 3;       // row group (32 rows each)
  const int half = w >> 2;    // KV half: 0 -> keys 0..1023, 1 -> 1024..2047

  // XCD-aware swizzle (bijective, 512 % 8 == 0)
  const int bid = blockIdx.x;
  const int wk = (bid & 7) * 64 + (bid >> 3);
  const int qt = wk & 15;  // 16 tiles x 128 rows
  const int hl = wk >> 4;  // b*16+h
  const int b_idx = hl >> 4, h = hl & 15;

  const bf16* Qh = Q + (size_t)hl * 131072;
  const int lo = l5h * 256 + l31 * 8;  // per-lane elem offset inside a fragment
  const bf16* kptr = Kp + (size_t)hl * 131072 + (size_t)(half * 16) * 4096 + lo;
  const bf16* vptr = Vp + (size_t)hl * 131072 + (size_t)(half * 16) * 4096 + lo;

  const int qbase = qt * 128 + rg * 32;
  const int qrow = qbase + l31;

  // Q fragments (B-operand of S^T): B[k=d][n=row]: lane n=l31, k=c*16+l5h*8+j
  short8 qf[4];
#pragma unroll
  for (int c = 0; c < 4; c++)
    qf[c] = *(const short8*)&Qh[(size_t)qrow * 64 + c * 16 + l5h * 8];

  floatx16 o_acc[2] = {};  // O^T: col=l31=row, d = dt*32 + (reg&3)+8*(reg>>2)+4*l5h
  float rsm0 = 0.f, rsm1 = 0.f, rsm2 = 0.f, rsm3 = 0.f;  // lane-local partials

  // preload K fragments of 32-key tile 0 (K packed: 32-key subtile stride 2048)
  short8 kf[4];
#pragma unroll
  for (int c = 0; c < 4; c++) kf[c] = *(const short8*)(kptr + c * 512);

#pragma unroll 1
  for (int it = 0; it < 32; ++it) {
    const int kv = it & 1;  // which 32-key half of the 64-key packed tile

    // S^T = K' Q^T : A = K'[key][d]: lane row=key=l31, k=l5h*8+j per c-chunk
    floatx16 s = {};
    __builtin_amdgcn_s_setprio(1);
#pragma unroll
    for (int c = 0; c < 4; c++) s = MFMA32(kf[c], qf[c], s);
    __builtin_amdgcn_s_setprio(0);

    // V loads for this tile, issued FIRST (in-order vmcnt => PV's wait doesn't
    // drain the K prefetch behind them)
    short8 vf[4];
#pragma unroll
    for (int dt = 0; dt < 2; dt++)
#pragma unroll
      for (int ch = 0; ch < 2; ch++)
        vf[dt * 2 + ch] = *(const short8*)(vptr + dt * 2048 + (kv * 2 + ch) * 512);

    // prefetch K fragments of next tile (kf dead after S-MFMAs)
    kptr += (it < 31) ? 2048 : 0;
#pragma unroll
    for (int c = 0; c < 4; c++) kf[c] = *(const short8*)(kptr + c * 512);

    // p = exp2(s) into FRESH scalars (no write-back into the AGPR-resident s)
    float e[16];
#pragma unroll
    for (int r = 0; r < 16; r += 4) {
      e[r + 0] = __builtin_amdgcn_exp2f(s[r + 0]);
      e[r + 1] = __builtin_amdgcn_exp2f(s[r + 1]);
      e[r + 2] = __builtin_amdgcn_exp2f(s[r + 2]);
      e[r + 3] = __builtin_amdgcn_exp2f(s[r + 3]);
      rsm0 += e[r + 0];
      rsm1 += e[r + 1];
      rsm2 += e[r + 2];
      rsm3 += e[r + 3];
    }

    // pf[ch][j] = P[key=ch*16+l5h*8+j][row=l31], built in-register (T12).
    short8 pf[2];
#pragma unroll
    for (int ch = 0; ch < 2; ch++) {
      const int rb = ch * 8;
      unsigned x0, x1, y0, y1;
      asm("v_cvt_pk_bf16_f32 %0, %1, %2" : "=v"(x0) : "v"(e[rb + 0]), "v"(e[rb + 1]));
      asm("v_cvt_pk_bf16_f32 %0, %1, %2" : "=v"(x1) : "v"(e[rb + 2]), "v"(e[rb + 3]));
      asm("v_cvt_pk_bf16_f32 %0, %1, %2" : "=v"(y0) : "v"(e[rb + 4]), "v"(e[rb + 5]));
      asm("v_cvt_pk_bf16_f32 %0, %1, %2" : "=v"(y1) : "v"(e[rb + 6]), "v"(e[rb + 7]));
      asm("v_permlane32_swap_b32 %0, %1" : "+v"(x0), "+v"(y0));
      asm("v_permlane32_swap_b32 %0, %1" : "+v"(x1), "+v"(y1));
      union { unsigned u[4]; short8 v; } cv;
      cv.u[0] = x0; cv.u[1] = x1; cv.u[2] = y0; cv.u[3] = y1;
      pf[ch] = cv.v;
    }

    // O^T += V^T P^T : A = V^T[d][key]: lane row=d=dt*32+l31 (per dt)
    __builtin_amdgcn_s_setprio(1);
#pragma unroll
    for (int dt = 0; dt < 2; dt++)
#pragma unroll
      for (int ch = 0; ch < 2; ch++)
        o_acc[dt] = MFMA32(vf[dt * 2 + ch], pf[ch], o_acc[dt]);
    __builtin_amdgcn_s_setprio(0);

    vptr += kv ? 4096 : 0;  // V packed-tile (64-key) stride, advance every 2 iters
  }

  // deferred rsum: one cross-half-of-wave shfl for this wave's 1024 keys
  float rsum = (rsm0 + rsm1) + (rsm2 + rsm3);
  rsum += __shfl_xor(rsum, 32, 64);

  // ---- combine KV halves: waves 4-7 hand o_acc/rsum to partner via LDS ----
  if (w >= 4) {
    const int slot = (w - 4) * 64 + lane;
    float4* dst = (float4*)(cb + (size_t)slot * 32);
#pragma unroll
    for (int dt = 0; dt < 2; dt++)
#pragma unroll
      for (int q = 0; q < 4; q++) {
        float4 v = make_float4(o_acc[dt][q * 4 + 0], o_acc[dt][q * 4 + 1],
                               o_acc[dt][q * 4 + 2], o_acc[dt][q * 4 + 3]);
        dst[(dt * 4 + q) ^ (lane & 7)] = v;  // xor-swizzle: conflict-free
      }
    rbuf[slot] = rsum;
  }
  __syncthreads();
  if (w < 4) {
    const int slot = w * 64 + lane;
    const float4* src = (const float4*)(cb + (size_t)slot * 32);
#pragma unroll
    for (int dt = 0; dt < 2; dt++)
#pragma unroll
      for (int q = 0; q < 4; q++) {
        float4 v = src[(dt * 4 + q) ^ (lane & 7)];
        o_acc[dt][q * 4 + 0] += v.x;
        o_acc[dt][q * 4 + 1] += v.y;
        o_acc[dt][q * 4 + 2] += v.z;
        o_acc[dt][q * 4 + 3] += v.w;
      }
    rsum += rbuf[slot];

    // epilogue: lane owns q-row qbase+l31; AO linear [b*2048+n][1024], col=h*64+d
    const float rinv = 1.f / rsum;
    bf16* orow = AO + (size_t)(b_idx * 2048 + qbase + l31) * 1024 + h * 64;
#pragma unroll
    for (int dt = 0; dt < 2; dt++)
#pragma unroll
      for (int rg2 = 0; rg2 < 4; rg2++) {
        ushort4 u;
        u.x = bfbits(o_acc[dt][rg2 * 4 + 0] * rinv);
        u.y = bfbits(o_acc[dt][rg2 * 4 + 1] * rinv);
        u.z = bfbits(o_acc[dt][rg2 * 4 + 2] * rinv);
        u.w = bfbits(o_acc[dt][rg2 * 4 + 3] * rinv);
        *(ushort4*)&orow[dt * 32 + rg2 * 8 + l5h * 4] = u;
      }
  }
}

extern "C" void kernel_launch(void* const* d_in, const int* in_sizes, int n_in,
                              void* d_out, int out_size, void* d_ws, size_t ws_size,
                              hipStream_t stream) {
  const void* x     = d_in[0];  // [2,2048,1024]  bf16 or fp32 (probed)
  const void* mask  = d_in[1];  // [2,2048]
  const void* w_qkv = d_in[2];  // [1024,3072]
  const void* w_out = d_in[3];  // [1024,1024]

  bf16* ws    = (bf16*)d_ws;
  bf16* xb    = ws;                     // 4194304 (fp32 path only; dead after gemm1)
  bf16* AO    = ws;                     // alias of xb, linear [4096,1024]
  bf16* wqkvT = ws + 4194304;           // 3145728
  bf16* woutT = wqkvT + 3145728;        // 1048576
  bf16* Qb    = woutT + 1048576;        // 4194304
  bf16* Kp    = Qb + 4194304;           // 4194304 (fragment-packed K)
  bf16* maskb = Kp + 4194304;           // 4096
  int*  flag  = (int*)(maskb + 4096);
  bf16* Vp    = (bf16*)d_out;           // 4194304 packed V (dead before gemm2 writes)

  prep_k<<<8193, 256, 0, stream>>>(mask, maskb, flag, x, xb, w_qkv, wqkvT,
                                   w_out, woutT);
  gemm_k<0><<<dim3(24, 32), 256, 0, stream>>>(xb, (const bf16*)x, wqkvT, Qb, Kp, Vp,
                                              nullptr, maskb, flag);
  flash_k<<<512, 512, 0, stream>>>(Qb, Kp, Vp, AO);
  gemm_k<1><<<dim3(8, 32), 256, 0, stream>>>(AO, nullptr, woutT, nullptr, nullptr,
                                             nullptr, d_out, nullptr, flag);
}